// Round 1
// baseline (347.439 us; speedup 1.0000x reference)
//
#include <hip/hip_runtime.h>
#include <cstdio>

// Problem constants
constexpr int B_   = 2;
constexpr int S_   = 2048;
constexpr int D_   = 1024;
constexpr int H_   = 16;
constexpr int DFF_ = 4096;
constexpr int DK_  = D_ / H_;   // 64
constexpr int M_   = B_ * S_;   // 4096 tokens
constexpr float EPS_ = 1e-5f;
constexpr size_t MEGE = 1u << 20;          // 1M elems
constexpr size_t QKV_STRIDE = 4 * MEGE;    // Q->K->V slot stride (elems)

typedef __attribute__((ext_vector_type(8))) short bf16x8;
typedef __attribute__((ext_vector_type(4))) float f32x4;

// ---------- bf16 helpers ----------
__device__ __forceinline__ float bf2f(unsigned int u) {
    return __uint_as_float(u << 16);
}
__device__ __forceinline__ unsigned short f2bf(float f) {          // RTNE
    unsigned int u = __float_as_uint(f);
    unsigned int r = u + 0x7fffu + ((u >> 16) & 1u);
    return (unsigned short)(r >> 16);
}
__device__ __forceinline__ unsigned short f2bf_rz(float f) {       // truncate (P matrix only)
    return (unsigned short)(__float_as_uint(f) >> 16);
}

// ---------- async global->LDS, 16B per lane ----------
__device__ __forceinline__ void gload_lds16(const unsigned short* g, unsigned short* l) {
    __builtin_amdgcn_global_load_lds(
        (const __attribute__((address_space(1))) unsigned int*)g,
        (__attribute__((address_space(3))) unsigned int*)l, 16, 0, 0);
}

// ---------- weight transpose+convert: W[K,N] f32 -> Wt[N,K] bf16 ----------
__global__ __launch_bounds__(256)
void tconv_k(const float* __restrict__ W, unsigned short* __restrict__ Wt, int K, int N)
{
    __shared__ float t[32][33];
    const int tx = threadIdx.x & 31, ty = threadIdx.x >> 5;   // 32 x 8
    const int n0 = blockIdx.x * 32, k0 = blockIdx.y * 32;
    #pragma unroll
    for (int p = 0; p < 4; ++p)
        t[ty + p * 8][tx] = W[(size_t)(k0 + ty + p * 8) * N + n0 + tx];
    __syncthreads();
    #pragma unroll
    for (int p = 0; p < 4; ++p)
        Wt[(size_t)(n0 + ty + p * 8) * K + k0 + tx] = f2bf(t[tx][ty + p * 8]);
}

// fused 4x DxD transpose (wq,wk,wv,wo) via blockIdx.z
__global__ __launch_bounds__(256)
void tconv4_k(const float* __restrict__ a, const float* __restrict__ b,
              const float* __restrict__ c, const float* __restrict__ d,
              unsigned short* __restrict__ oa, unsigned short* __restrict__ ob,
              unsigned short* __restrict__ oc, unsigned short* __restrict__ od)
{
    const int z = blockIdx.z;
    const float* W = (z == 0) ? a : (z == 1) ? b : (z == 2) ? c : d;
    unsigned short* Wt = (z == 0) ? oa : (z == 1) ? ob : (z == 2) ? oc : od;
    __shared__ float t[32][33];
    const int tx = threadIdx.x & 31, ty = threadIdx.x >> 5;
    const int n0 = blockIdx.x * 32, k0 = blockIdx.y * 32;
    #pragma unroll
    for (int p = 0; p < 4; ++p)
        t[ty + p * 8][tx] = W[(size_t)(k0 + ty + p * 8) * D_ + n0 + tx];
    __syncthreads();
    #pragma unroll
    for (int p = 0; p < 4; ++p)
        Wt[(size_t)(n0 + ty + p * 8) * D_ + k0 + tx] = f2bf(t[tx][ty + p * 8]);
}

// ---------- x f32 -> bf16 ----------
__global__ __launch_bounds__(256)
void cvtx_k(const float* __restrict__ in, unsigned short* __restrict__ out) {
    int i = blockIdx.x * 256 + threadIdx.x;
    float4 f = reinterpret_cast<const float4*>(in)[i];
    ushort4 u;
    u.x = f2bf(f.x); u.y = f2bf(f.y); u.z = f2bf(f.z); u.w = f2bf(f.w);
    reinterpret_cast<ushort4*>(out)[i] = u;
}

// ---------- phased MFMA GEMM: C = A[M,K] @ Bt[N,K]^T, bf16 in/out, fp32 accum ----
// 8-wave (2M x 4N), BN=256 fixed, BM in {256,128}. BK=64, double-buffered LDS,
// XOR chunk-swizzle (conflict-free ds_read_b128), counted vmcnt (never 0 in
// steady state), setprio around MFMA clusters. OMODE: 0 = flat [M,N];
// 2 = fused QKV (N=3072 -> 3 head tensors). Split-K via blockIdx.z.
//
// Staging unit = one 128row x 64col half-tile = 2 gload_lds16 per wave.
// BM=256 unit order/tile: {0:A-h0, 1:B-h0, 2:B-h1, 3:A-h1}; 4 phases/tile:
//   p0 (m0,n0): read A-h0 + B-h0      | stage (t+1, A-h1)
//   p1 (m0,n1): read B-h1             | stage (t+2, A-h0)
//   p2 (m1,n0): read A-h1 (reuse b0)  | stage (t+2, B-h0)
//   p3 (m1,n1): reuse regs            | stage (t+2, B-h1)
// boundary: vmcnt(6) (=3 units) / vmcnt(0) entering last tile; prologue = 7 units.
// BM=128 unit order/tile: {0:B-h0, 1:A-full, 2:B-h1}; 2 phases/tile:
//   p0 (n0): read A(all) + B-h0 | stage (t+1, B-h1)
//   p1 (n1): read B-h1          | stage (t+2, B-h0), (t+2, A)
// boundary: vmcnt(4) (=2 units) / vmcnt(0); prologue = 5 units.
// Hazard ledger: every slot's overwrite-issue is >=1 barrier after its last
// LDS read (A/B frags register-held across phases, never re-read).
template<int BM, int OMODE, bool RELU>
__global__ __launch_bounds__(512, 2)
void mg2_k(const unsigned short* __restrict__ A,
           const unsigned short* __restrict__ Bt,
           const float* __restrict__ bias,
           unsigned short* __restrict__ C,
           int M, int N, int K, int Kld)
{
    constexpr int MI  = BM / 64;            // A frags per m-half (256->4, 128->2)
    constexpr int AMH = (BM == 128) ? 2 : 1;
    __shared__ __align__(16) unsigned short As[2][BM * 64];
    __shared__ __align__(16) unsigned short Bs[2][256 * 64];

    const int z = blockIdx.z;
    A  += (size_t)z * K;
    Bt += (size_t)z * K;
    C  += (size_t)z * ((size_t)M * N);

    const int tid  = threadIdx.x;
    const int w    = tid >> 6, lane = tid & 63;
    const int l15  = lane & 15, quad = lane >> 4;
    const int wm   = w >> 2, wn = w & 3;            // 2M x 4N wave grid
    const int m0   = blockIdx.y * BM, n0 = blockIdx.x * 256;
    const int NT   = K >> 6;

    // staging lane decode: lane l writes LDS row (8*g + l/8), chunk l%8 of its
    // wave's 16-row slab; source chunk is pre-swizzled so LDS(row,c) holds
    // global chunk c ^ (row&7).
    const int srow = lane >> 3;
    const int schk = (lane & 7) ^ srow;
    const int rsw  = l15 & 7;                        // read-side swizzle key

    f32x4 acc[2][MI][2][2];                          // [mh][mi][nh][nj]
    #pragma unroll
    for (int mh = 0; mh < 2; ++mh)
        #pragma unroll
        for (int mi = 0; mi < MI; ++mi)
            #pragma unroll
            for (int nh = 0; nh < 2; ++nh)
                #pragma unroll
                for (int nj = 0; nj < 2; ++nj)
                    acc[mh][mi][nh][nj] = (f32x4){0.f, 0.f, 0.f, 0.f};

    bf16x8 aA[AMH][MI][2];
    bf16x8 b0[2][2], b1[2][2];

    auto stage = [&](int tile, int type) {
        if (tile >= NT) return;
        const int buf = tile & 1;
        unsigned short* dst; const unsigned short* src; int r0;
        if (BM == 256) {
            if      (type == 0) { dst = &As[buf][0];        src = A;  r0 = m0; }
            else if (type == 1) { dst = &Bs[buf][0];        src = Bt; r0 = n0; }
            else if (type == 2) { dst = &Bs[buf][128 * 64]; src = Bt; r0 = n0 + 128; }
            else                { dst = &As[buf][128 * 64]; src = A;  r0 = m0 + 128; }
        } else {
            if      (type == 0) { dst = &Bs[buf][0];        src = Bt; r0 = n0; }
            else if (type == 1) { dst = &As[buf][0];        src = A;  r0 = m0; }
            else                { dst = &Bs[buf][128 * 64]; src = Bt; r0 = n0 + 128; }
        }
        const int k0 = tile * 64;
        #pragma unroll
        for (int g = 0; g < 2; ++g) {
            const int r = w * 16 + g * 8 + srow;
            gload_lds16(src + (size_t)(r0 + r) * Kld + k0 + schk * 8,
                        dst + (w * 16 + g * 8) * 64);
        }
    };
    auto rdA = [&](int buf, int mh, int amh) {
        const unsigned short* base = &As[buf][(BM == 256 && mh) ? 128 * 64 : 0];
        #pragma unroll
        for (int mi = 0; mi < MI; ++mi) {
            const int row = (BM == 256) ? (wm * 64 + mi * 16 + l15)
                                        : (wm * 64 + mh * 32 + mi * 16 + l15);
            const unsigned short* rp = base + row * 64;
            aA[amh][mi][0] = *reinterpret_cast<const bf16x8*>(rp + ((quad    ) ^ rsw) * 8);
            aA[amh][mi][1] = *reinterpret_cast<const bf16x8*>(rp + ((quad + 4) ^ rsw) * 8);
        }
    };
    auto rdB = [&](int buf, int nh, bf16x8 (&b)[2][2]) {
        const unsigned short* base = &Bs[buf][nh ? 128 * 64 : 0];
        #pragma unroll
        for (int nj = 0; nj < 2; ++nj) {
            const int row = wn * 32 + nj * 16 + l15;
            const unsigned short* rp = base + row * 64;
            b[nj][0] = *reinterpret_cast<const bf16x8*>(rp + ((quad    ) ^ rsw) * 8);
            b[nj][1] = *reinterpret_cast<const bf16x8*>(rp + ((quad + 4) ^ rsw) * 8);
        }
    };
    auto mm = [&](int mh, int amh, int nh, bf16x8 (&b)[2][2]) {
        __builtin_amdgcn_s_setprio(1);
        #pragma unroll
        for (int mi = 0; mi < MI; ++mi)
            #pragma unroll
            for (int nj = 0; nj < 2; ++nj) {
                acc[mh][mi][nh][nj] = __builtin_amdgcn_mfma_f32_16x16x32_bf16(
                    aA[amh][mi][0], b[nj][0], acc[mh][mi][nh][nj], 0, 0, 0);
                acc[mh][mi][nh][nj] = __builtin_amdgcn_mfma_f32_16x16x32_bf16(
                    aA[amh][mi][1], b[nj][1], acc[mh][mi][nh][nj], 0, 0, 0);
            }
        __builtin_amdgcn_s_setprio(0);
    };

    // prologue: stage tile0 fully + first (BM==256 ? 3 : 2) units of tile1
    if (BM == 256) {
        stage(0, 0); stage(0, 1); stage(0, 2); stage(0, 3);
        stage(1, 0); stage(1, 1); stage(1, 2);
    } else {
        stage(0, 0); stage(0, 1); stage(0, 2);
        stage(1, 0); stage(1, 1);
    }

    for (int t = 0; t < NT; ++t) {
        const int cur = t & 1;
        // tile boundary: entering tile t's buffer must be fully landed.
        if (t == NT - 1)    asm volatile("s_waitcnt vmcnt(0)" ::: "memory");
        else if (BM == 256) asm volatile("s_waitcnt vmcnt(6)" ::: "memory");
        else                asm volatile("s_waitcnt vmcnt(4)" ::: "memory");
        __builtin_amdgcn_s_barrier();

        if (BM == 256) {
            // p0: (m0,n0)
            rdA(cur, 0, 0); rdB(cur, 0, b0); stage(t + 1, 3);
            __builtin_amdgcn_s_barrier();
            asm volatile("s_waitcnt lgkmcnt(0)" ::: "memory");
            mm(0, 0, 0, b0);
            __builtin_amdgcn_s_barrier();
            // p1: (m0,n1)
            rdB(cur, 1, b1); stage(t + 2, 0);
            __builtin_amdgcn_s_barrier();
            asm volatile("s_waitcnt lgkmcnt(0)" ::: "memory");
            mm(0, 0, 1, b1);
            __builtin_amdgcn_s_barrier();
            // p2: (m1,n0)
            rdA(cur, 1, 0); stage(t + 2, 1);
            __builtin_amdgcn_s_barrier();
            asm volatile("s_waitcnt lgkmcnt(0)" ::: "memory");
            mm(1, 0, 0, b0);
            __builtin_amdgcn_s_barrier();
            // p3: (m1,n1)
            stage(t + 2, 2);
            __builtin_amdgcn_s_barrier();
            asm volatile("s_waitcnt lgkmcnt(0)" ::: "memory");
            mm(1, 0, 1, b1);
            // tile-end barrier = next loop-top barrier (after boundary vmcnt)
        } else {
            // p0: nh=0 (both m-halves)
            rdA(cur, 0, 0); rdA(cur, 1, 1); rdB(cur, 0, b0); stage(t + 1, 2);
            __builtin_amdgcn_s_barrier();
            asm volatile("s_waitcnt lgkmcnt(0)" ::: "memory");
            mm(0, 0, 0, b0); mm(1, 1, 0, b0);
            __builtin_amdgcn_s_barrier();
            // p1: nh=1
            rdB(cur, 1, b1); stage(t + 2, 0); stage(t + 2, 1);
            __builtin_amdgcn_s_barrier();
            asm volatile("s_waitcnt lgkmcnt(0)" ::: "memory");
            mm(0, 0, 1, b1); mm(1, 1, 1, b1);
        }
    }

    // epilogue (vmcnt already 0: last tile boundary drained, tail stages skipped)
    #pragma unroll
    for (int mh = 0; mh < 2; ++mh)
        #pragma unroll
        for (int mi = 0; mi < MI; ++mi) {
            const int mrow = (BM == 256) ? (mh * 128 + wm * 64 + mi * 16)
                                         : (wm * 64 + mh * 32 + mi * 16);
            #pragma unroll
            for (int r = 0; r < 4; ++r) {
                const int m = m0 + mrow + quad * 4 + r;
                #pragma unroll
                for (int nh = 0; nh < 2; ++nh)
                    #pragma unroll
                    for (int nj = 0; nj < 2; ++nj) {
                        const int n = n0 + nh * 128 + wn * 32 + nj * 16 + l15;
                        float v = acc[mh][mi][nh][nj][r];
                        if (bias) v += bias[n];
                        if (RELU) v = fmaxf(v, 0.0f);
                        size_t o;
                        if (OMODE == 2) {
                            int mat = n >> 10, nn = n & 1023;
                            int b = m >> 11, s = m & 2047;
                            int h = nn >> 6, dk = nn & 63;
                            o = (size_t)mat * QKV_STRIDE + (((size_t)b * H_ + h) * S_ + s) * DK_ + dk;
                        } else {
                            o = (size_t)m * N + n;
                        }
                        C[o] = f2bf(v);
                    }
            }
        }
}

// ---------- wave reduction ----------
__device__ __forceinline__ float wave_sum(float v) {
    #pragma unroll
    for (int off = 32; off > 0; off >>= 1) v += __shfl_down(v, off, 64);
    return v;
}

// ---------- flash attention v3 (MFMA): one block = (bh, 128-query tile) ----------
constexpr int TQ_ = 128;       // 4 waves x 32 queries
constexpr int TK_ = 64;
constexpr int LP_ = 72;        // padded LDS row (bf16 elems)
constexpr int NT_ = S_ / TK_;  // 32 kv tiles

__global__ __launch_bounds__(256)
void fattn_k(const unsigned short* __restrict__ Qm, const unsigned short* __restrict__ Km,
             const unsigned short* __restrict__ Vm, unsigned short* __restrict__ O)
{
    const int bh  = blockIdx.x >> 4;     // 16 q-tiles per (b,h)
    const int qt  = blockIdx.x & 15;
    const int tid = threadIdx.x;
    const int w = tid >> 6, lane = tid & 63;
    const int quad = lane >> 4, l15 = lane & 15;

    __shared__ unsigned short Ks[2][TK_][LP_];       // K tile [kpos][d]
    __shared__ unsigned short Vt[2][DK_ + 16][LP_];  // V^T [d][col'] + ones rows 64..79
    __shared__ unsigned short Ps[4][32][LP_];        // per-wave P [q][col']

    bf16x8 qf[2][2];
    #pragma unroll
    for (int i = 0; i < 2; ++i) {
        const unsigned short* qp = Qm + ((size_t)bh * S_ + qt * TQ_ + w * 32 + i * 16 + l15) * DK_;
        qf[i][0] = *reinterpret_cast<const bf16x8*>(qp + quad * 8);
        qf[i][1] = *reinterpret_cast<const bf16x8*>(qp + 32 + quad * 8);
    }

    f32x4 o[2][4];
    f32x4 o4[2];
    #pragma unroll
    for (int i = 0; i < 2; ++i) {
        #pragma unroll
        for (int n = 0; n < 4; ++n) o[i][n] = (f32x4){0.f, 0.f, 0.f, 0.f};
        o4[i] = (f32x4){0.f, 0.f, 0.f, 0.f};
    }

    const unsigned short* kg0 = Km + (size_t)bh * S_ * DK_;
    const unsigned short* vg0 = Vm + (size_t)bh * S_ * DK_;
    const int dgrp = tid >> 4;
    const int vkp  = tid & 15;

    {
        const uint4* kg = reinterpret_cast<const uint4*>(kg0);
        #pragma unroll
        for (int p = 0; p < 2; ++p) {
            int idx = p * 256 + tid;
            *reinterpret_cast<uint4*>(&Ks[0][idx >> 3][(idx & 7) * 8]) = kg[idx];
        }
        ushort4 vp[4];
        #pragma unroll
        for (int p = 0; p < 4; ++p)
            vp[p] = reinterpret_cast<const ushort4*>(vg0 + (size_t)(vkp + p * 16) * DK_)[dgrp];
        ushort4 pk;
        pk.x = vp[0].x; pk.y = vp[1].x; pk.z = vp[2].x; pk.w = vp[3].x;
        *reinterpret_cast<ushort4*>(&Vt[0][dgrp * 4 + 0][vkp * 4]) = pk;
        pk.x = vp[0].y; pk.y = vp[1].y; pk.z = vp[2].y; pk.w = vp[3].y;
        *reinterpret_cast<ushort4*>(&Vt[0][dgrp * 4 + 1][vkp * 4]) = pk;
        pk.x = vp[0].z; pk.y = vp[1].z; pk.z = vp[2].z; pk.w = vp[3].z;
        *reinterpret_cast<ushort4*>(&Vt[0][dgrp * 4 + 2][vkp * 4]) = pk;
        pk.x = vp[0].w; pk.y = vp[1].w; pk.z = vp[2].w; pk.w = vp[3].w;
        *reinterpret_cast<ushort4*>(&Vt[0][dgrp * 4 + 3][vkp * 4]) = pk;
        for (int idx = tid; idx < 2 * 16 * LP_; idx += 256) {
            int b  = idx / (16 * LP_);
            int rr = (idx / LP_) % 16;
            int cc = idx % LP_;
            Vt[b][64 + rr][cc] = (rr == 0) ? (unsigned short)0x3F80 : (unsigned short)0;
        }
    }

    for (int t = 0; t < NT_; ++t) {
        const int cur = t & 1, nxt = cur ^ 1;
        __syncthreads();

        uint4 kpre0, kpre1;
        ushort4 vp[4];
        const bool hn = (t + 1 < NT_);
        if (hn) {
            const uint4* kg = reinterpret_cast<const uint4*>(kg0 + (size_t)(t + 1) * TK_ * DK_);
            kpre0 = kg[tid];
            kpre1 = kg[256 + tid];
            const unsigned short* vg = vg0 + (size_t)(t + 1) * TK_ * DK_;
            #pragma unroll
            for (int p = 0; p < 4; ++p)
                vp[p] = reinterpret_cast<const ushort4*>(vg + (size_t)(vkp + p * 16) * DK_)[dgrp];
        }

        f32x4 s[2][4];
        #pragma unroll
        for (int n = 0; n < 4; ++n) {
            bf16x8 b0 = *reinterpret_cast<const bf16x8*>(&Ks[cur][n * 16 + l15][quad * 8]);
            bf16x8 b1 = *reinterpret_cast<const bf16x8*>(&Ks[cur][n * 16 + l15][32 + quad * 8]);
            #pragma unroll
            for (int i = 0; i < 2; ++i) {
                f32x4 a2 = (f32x4){0.f, 0.f, 0.f, 0.f};
                a2 = __builtin_amdgcn_mfma_f32_16x16x32_bf16(qf[i][0], b0, a2, 0, 0, 0);
                a2 = __builtin_amdgcn_mfma_f32_16x16x32_bf16(qf[i][1], b1, a2, 0, 0, 0);
                s[i][n] = a2;
            }
        }

        #pragma unroll
        for (int i = 0; i < 2; ++i)
            #pragma unroll
            for (int r = 0; r < 4; ++r) {
                ushort4 pk;
                pk.x = f2bf_rz(__expf(s[i][0][r] * 0.125f));
                pk.y = f2bf_rz(__expf(s[i][1][r] * 0.125f));
                pk.z = f2bf_rz(__expf(s[i][2][r] * 0.125f));
                pk.w = f2bf_rz(__expf(s[i][3][r] * 0.125f));
                *reinterpret_cast<ushort4*>(&Ps[w][i * 16 + quad * 4 + r][l15 * 4]) = pk;
            }

        if (hn) {
            *reinterpret_cast<uint4*>(&Ks[nxt][tid >> 3][(tid & 7) * 8]) = kpre0;
            int idx = 256 + tid;
            *reinterpret_cast<uint4*>(&Ks[nxt][idx >> 3][(idx & 7) * 8]) = kpre1;
            ushort4 pk;
            pk.x = vp[0].x; pk.y = vp[1].x; pk.z = vp[2].x; pk.w = vp[3].x;
            *reinterpret_cast<ushort4*>(&Vt[nxt][dgrp * 4 + 0][vkp * 4]) = pk;
            pk.x = vp[0].y; pk.y = vp[1].y; pk.z = vp[2].y; pk.w = vp[3].y;
            *reinterpret_cast<ushort4*>(&Vt[nxt][dgrp * 4 + 1][vkp * 4]) = pk;
            pk.x = vp[0].z; pk.y = vp[1].z; pk.z = vp[2].z; pk.w = vp[3].z;
            *reinterpret_cast<ushort4*>(&Vt[nxt][dgrp * 4 + 2][vkp * 4]) = pk;
            pk.x = vp[0].w; pk.y = vp[1].w; pk.z = vp[2].w; pk.w = vp[3].w;
            *reinterpret_cast<ushort4*>(&Vt[nxt][dgrp * 4 + 3][vkp * 4]) = pk;
        }
        __syncthreads();

        bf16x8 pa[2][2];
        #pragma unroll
        for (int i = 0; i < 2; ++i) {
            pa[i][0] = *reinterpret_cast<const bf16x8*>(&Ps[w][i * 16 + l15][quad * 8]);
            pa[i][1] = *reinterpret_cast<const bf16x8*>(&Ps[w][i * 16 + l15][32 + quad * 8]);
        }
        #pragma unroll
        for (int n = 0; n < 4; ++n) {
            bf16x8 vb0 = *reinterpret_cast<const bf16x8*>(&Vt[cur][n * 16 + l15][quad * 8]);
            bf16x8 vb1 = *reinterpret_cast<const bf16x8*>(&Vt[cur][n * 16 + l15][32 + quad * 8]);
            #pragma unroll
            for (int i = 0; i < 2; ++i) {
                o[i][n] = __builtin_amdgcn_mfma_f32_16x16x32_bf16(pa[i][0], vb0, o[i][n], 0, 0, 0);
                o[i][n] = __builtin_amdgcn_mfma_f32_16x16x32_bf16(pa[i][1], vb1, o[i][n], 0, 0, 0);
            }
        }
        {
            bf16x8 vb40 = *reinterpret_cast<const bf16x8*>(&Vt[cur][64 + l15][quad * 8]);
            bf16x8 vb41 = *reinterpret_cast<const bf16x8*>(&Vt[cur][64 + l15][32 + quad * 8]);
            #pragma unroll
            for (int i = 0; i < 2; ++i) {
                o4[i] = __builtin_amdgcn_mfma_f32_16x16x32_bf16(pa[i][0], vb40, o4[i], 0, 0, 0);
                o4[i] = __builtin_amdgcn_mfma_f32_16x16x32_bf16(pa[i][1], vb41, o4[i], 0, 0, 0);
            }
        }
    }

    const int b = bh >> 4, h = bh & 15;
    #pragma unroll
    for (int i = 0; i < 2; ++i)
        #pragma unroll
        for (int r = 0; r < 4; ++r) {
            float lrv = __shfl(o4[i][r], lane & 0x30, 64);
            float inv = 1.0f / lrv;
            int q = qt * TQ_ + w * 32 + i * 16 + quad * 4 + r;
            unsigned short* op = O + ((size_t)b * S_ + q) * D_ + h * DK_;
            #pragma unroll
            for (int n = 0; n < 4; ++n)
                op[n * 16 + l15] = f2bf(o[i][n][r] * inv);
        }
}

// ---------- reducing LayerNorm: v = P0+P1 (+bias) (+res), then LN (ddof=1) ----------
template<bool HAS_BIAS, bool RES_F32, bool OUT_F32>
__global__ __launch_bounds__(256)
void lnr_k(const unsigned short* __restrict__ P0, const unsigned short* __restrict__ P1,
           const void* __restrict__ res, const float* __restrict__ bias,
           const float* __restrict__ gp, const float* __restrict__ bp,
           void* __restrict__ Out)
{
    const int row = blockIdx.x;
    const int tid = threadIdx.x;
    const int lane = tid & 63, wave = tid >> 6;
    __shared__ float rs[4], rss[4];

    const size_t i4 = (size_t)row * 256 + tid;
    const ushort4 a = reinterpret_cast<const ushort4*>(P0)[i4];
    const ushort4 b = reinterpret_cast<const ushort4*>(P1)[i4];
    float v0 = bf2f(a.x) + bf2f(b.x);
    float v1 = bf2f(a.y) + bf2f(b.y);
    float v2 = bf2f(a.z) + bf2f(b.z);
    float v3 = bf2f(a.w) + bf2f(b.w);
    if (RES_F32) {
        float4 rv = reinterpret_cast<const float4*>(res)[i4];
        v0 += rv.x; v1 += rv.y; v2 += rv.z; v3 += rv.w;
    } else {
        ushort4 rv = reinterpret_cast<const ushort4*>(res)[i4];
        v0 += bf2f(rv.x); v1 += bf2f(rv.y); v2 += bf2f(rv.z); v3 += bf2f(rv.w);
    }
    if (HAS_BIAS) {
        float4 bv = reinterpret_cast<const float4*>(bias)[tid];
        v0 += bv.x; v1 += bv.y; v2 += bv.z; v3 += bv.w;
    }

    float s  = v0 + v1 + v2 + v3;
    float ss = v0*v0 + v1*v1 + v2*v2 + v3*v3;
    s = wave_sum(s);
    ss = wave_sum(ss);
    if (lane == 0) { rs[wave] = s; rss[wave] = ss; }
    __syncthreads();
    const float stot  = rs[0] + rs[1] + rs[2] + rs[3];
    const float sstot = rss[0] + rss[1] + rss[2] + rss[3];
    const float mean = stot / (float)D_;
    const float var  = (sstot - (float)D_ * mean * mean) / (float)(D_ - 1);
    const float scl = gp[0] * rsqrtf(var + EPS_);
    const float be = bp[0];

    float o0 = (v0 - mean) * scl + be;
    float o1 = (v1 - mean) * scl + be;
    float o2 = (v2 - mean) * scl + be;
    float o3 = (v3 - mean) * scl + be;
    if (OUT_F32) {
        reinterpret_cast<float4*>(Out)[i4] = make_float4(o0, o1, o2, o3);
    } else {
        ushort4 o;
        o.x = f2bf(o0); o.y = f2bf(o1); o.z = f2bf(o2); o.w = f2bf(o3);
        reinterpret_cast<ushort4*>(Out)[i4] = o;
    }
}

// ---------- host launch ----------
extern "C" void kernel_launch(void* const* d_in, const int* in_sizes, int n_in,
                              void* d_out, int out_size, void* d_ws, size_t ws_size,
                              hipStream_t stream)
{
    const float* x   = (const float*)d_in[0];
    const float* wq  = (const float*)d_in[2];
    const float* wk  = (const float*)d_in[3];
    const float* wv  = (const float*)d_in[4];
    const float* wo  = (const float*)d_in[5];
    const float* w1  = (const float*)d_in[6];
    const float* b1  = (const float*)d_in[7];
    const float* w2  = (const float*)d_in[8];
    const float* b2  = (const float*)d_in[9];
    const float* g1  = (const float*)d_in[10];
    const float* be1 = (const float*)d_in[11];
    const float* g2  = (const float*)d_in[12];
    const float* be2 = (const float*)d_in[13];

    unsigned short* ws = (unsigned short*)d_ws;
    const size_t need_bytes = 32 * MEGE * 2;           // 64 MB peak
    if (ws_size < need_bytes) {
        fprintf(stderr, "kernel_launch: ws too small (%zu < %zu)\n", ws_size, need_bytes);
    }
    // bf16 workspace layout (elems), liveness-packed:
    //   0-4   : wqt,wkt,wvt,wot (dead after Wo)   -> FFN-down partials FP (0-8)
    //   4-8   : w1t [DFF,D]     (dead after FFN-up)
    //   8-12  : w2t [D,DFF]
    //   12-16 : xb -> x1 (LN1 writes here)
    //   16-32 : Q,K,V,AO -> Wo partials WP (16-24, over dead Q,K) -> h1 full (16-32)
    unsigned short* wqt = ws + 0 * MEGE;
    unsigned short* wkt = ws + 1 * MEGE;
    unsigned short* wvt = ws + 2 * MEGE;
    unsigned short* wot = ws + 3 * MEGE;
    unsigned short* w1t = ws + 4 * MEGE;
    unsigned short* w2t = ws + 8 * MEGE;
    unsigned short* xb  = ws + 12 * MEGE;
    unsigned short* Q   = ws + 16 * MEGE;  // Q,K,V contiguous (QKV_STRIDE apart)
    unsigned short* K   = ws + 20 * MEGE;
    unsigned short* V   = ws + 24 * MEGE;
    unsigned short* AO  = ws + 28 * MEGE;
    unsigned short* x1  = xb;              // LN1 output (xb dead after QKV)
    unsigned short* WP  = ws + 16 * MEGE;  // Wo split-K partials [2][M,D] over dead Q,K
    unsigned short* h1  = ws + 16 * MEGE;  // full [4096,4096] (after LN1)
    unsigned short* FP  = ws + 0 * MEGE;   // FFN-down partials [2][M,D] over dead wqt..w1t

    // 0) weight transpose+convert + x convert
    tconv4_k<<<dim3(D_ / 32, D_ / 32, 4), 256, 0, stream>>>(wq, wk, wv, wo, wqt, wkt, wvt, wot);
    tconv_k<<<dim3(DFF_ / 32, D_ / 32), 256, 0, stream>>>(w1, w1t, D_, DFF_);
    tconv_k<<<dim3(D_ / 32, DFF_ / 32), 256, 0, stream>>>(w2, w2t, DFF_, D_);
    cvtx_k<<<dim3(M_ * D_ / 1024), 256, 0, stream>>>(x, xb);

    // 1) fused QKV projection: 256-wide phased pipeline, 192 blocks (BM=256)
    mg2_k<256, 2, false><<<dim3(3 * D_ / 256, M_ / 256), 512, 0, stream>>>(
        xb, wqt, nullptr, Q, M_, 3 * D_, D_, D_);

    // 2) flash attention: 512 blocks
    fattn_k<<<dim3(B_ * H_ * (S_ / TQ_)), 256, 0, stream>>>(Q, K, V, AO);

    // 3) Wo split-K=2 (BM=128): 256 blocks (1/CU), partials -> WP[2][M,D]
    mg2_k<128, 0, false><<<dim3(D_ / 256, M_ / 128, 2), 512, 0, stream>>>(
        AO, wot, nullptr, WP, M_, D_, D_ / 2, D_);

    // 4) LN1 = reduce(WP0+WP1) + x residual -> x1 (bf16)
    lnr_k<false, true, false><<<dim3(M_), 256, 0, stream>>>(
        WP, WP + 4 * MEGE, x, nullptr, g1, be1, x1);

    // 5) FFN-up (BM=256): 256 blocks (1/CU)
    mg2_k<256, 0, true><<<dim3(DFF_ / 256, M_ / 256), 512, 0, stream>>>(
        x1, w1t, b1, h1, M_, DFF_, D_, D_);

    // 6) FFN-down split-K=2 (BM=128): 256 blocks, partials -> FP[2][M,D]
    mg2_k<128, 0, false><<<dim3(D_ / 256, M_ / 128, 2), 512, 0, stream>>>(
        h1, w2t, nullptr, FP, M_, D_, DFF_ / 2, DFF_);

    // 7) LN2 = reduce(FP0+FP1) + b2 + x1 residual -> fp32 output
    lnr_k<true, false, true><<<dim3(M_), 256, 0, stream>>>(
        FP, FP + 4 * MEGE, x1, b2, g2, be2, d_out);
}

// Round 2
// 342.311 us; speedup vs baseline: 1.0150x; 1.0150x over previous
//
#include <hip/hip_runtime.h>
#include <cstdio>

// Problem constants
constexpr int B_   = 2;
constexpr int S_   = 2048;
constexpr int D_   = 1024;
constexpr int H_   = 16;
constexpr int DFF_ = 4096;
constexpr int DK_  = D_ / H_;   // 64
constexpr int M_   = B_ * S_;   // 4096 tokens
constexpr float EPS_ = 1e-5f;
constexpr size_t MEGE = 1u << 20;          // 1M elems
constexpr size_t QKV_STRIDE = 4 * MEGE;    // Q->K->V slot stride (elems)

typedef __attribute__((ext_vector_type(8))) short bf16x8;
typedef __attribute__((ext_vector_type(4))) float f32x4;

// ---------- bf16 helpers ----------
__device__ __forceinline__ float bf2f(unsigned int u) {
    return __uint_as_float(u << 16);
}
__device__ __forceinline__ unsigned short f2bf(float f) {          // RTNE
    unsigned int u = __float_as_uint(f);
    unsigned int r = u + 0x7fffu + ((u >> 16) & 1u);
    return (unsigned short)(r >> 16);
}
__device__ __forceinline__ unsigned short f2bf_rz(float f) {       // truncate (P matrix only)
    return (unsigned short)(__float_as_uint(f) >> 16);
}

// ---------- async global->LDS, 16B per lane ----------
__device__ __forceinline__ void gload_lds16(const unsigned short* g, unsigned short* l) {
    __builtin_amdgcn_global_load_lds(
        (const __attribute__((address_space(1))) unsigned int*)g,
        (__attribute__((address_space(3))) unsigned int*)l, 16, 0, 0);
}

// ---------- fused preprocessing: 6 weight transposes + x convert, ONE launch ----
// blocks [0,4096): wq/wk/wv/wo DxD transpose (z = bid>>10)
// blocks [4096,8192): w1 [D,DFF] -> w1t [DFF,D]
// blocks [8192,12288): w2 [DFF,D] -> w2t [D,DFF]
// blocks [12288,16384): x f32 -> bf16
__device__ __forceinline__ void tr32(const float* __restrict__ W, unsigned short* __restrict__ Wt,
                                     int K, int N, int bx, int by, float* t /*[32*33]*/)
{
    const int tx = threadIdx.x & 31, ty = threadIdx.x >> 5;   // 32 x 8
    const int n0 = bx * 32, k0 = by * 32;
    #pragma unroll
    for (int p = 0; p < 4; ++p)
        t[(ty + p * 8) * 33 + tx] = W[(size_t)(k0 + ty + p * 8) * N + n0 + tx];
    __syncthreads();
    #pragma unroll
    for (int p = 0; p < 4; ++p)
        Wt[(size_t)(n0 + ty + p * 8) * K + k0 + tx] = f2bf(t[tx * 33 + ty + p * 8]);
}

__global__ __launch_bounds__(256)
void prep_k(const float* __restrict__ wq, const float* __restrict__ wk,
            const float* __restrict__ wv, const float* __restrict__ wo,
            const float* __restrict__ w1, const float* __restrict__ w2,
            const float* __restrict__ x,
            unsigned short* __restrict__ wqt, unsigned short* __restrict__ wkt,
            unsigned short* __restrict__ wvt, unsigned short* __restrict__ wot,
            unsigned short* __restrict__ w1t, unsigned short* __restrict__ w2t,
            unsigned short* __restrict__ xb)
{
    __shared__ float t[32 * 33];
    const int bid = blockIdx.x;
    if (bid < 4096) {
        const int z = bid >> 10, rem = bid & 1023;
        const float* W = (z == 0) ? wq : (z == 1) ? wk : (z == 2) ? wv : wo;
        unsigned short* Wt = (z == 0) ? wqt : (z == 1) ? wkt : (z == 2) ? wvt : wot;
        tr32(W, Wt, D_, D_, rem & 31, rem >> 5, t);
    } else if (bid < 8192) {
        const int rem = bid - 4096;
        tr32(w1, w1t, D_, DFF_, rem & 127, rem >> 7, t);
    } else if (bid < 12288) {
        const int rem = bid - 8192;
        tr32(w2, w2t, DFF_, D_, rem & 31, rem >> 5, t);
    } else {
        const int i = (bid - 12288) * 256 + threadIdx.x;
        float4 f = reinterpret_cast<const float4*>(x)[i];
        ushort4 u;
        u.x = f2bf(f.x); u.y = f2bf(f.y); u.z = f2bf(f.z); u.w = f2bf(f.w);
        reinterpret_cast<ushort4*>(xb)[i] = u;
    }
}

// ---------- phased MFMA GEMM: C = A[M,K] @ Bt[N,K]^T, bf16 in/out, fp32 accum ----
// (unchanged from R1 — verified 347 µs pipeline)
template<int BM, int OMODE, bool RELU>
__global__ __launch_bounds__(512, 2)
void mg2_k(const unsigned short* __restrict__ A,
           const unsigned short* __restrict__ Bt,
           const float* __restrict__ bias,
           unsigned short* __restrict__ C,
           int M, int N, int K, int Kld)
{
    constexpr int MI  = BM / 64;            // A frags per m-half (256->4, 128->2)
    constexpr int AMH = (BM == 128) ? 2 : 1;
    __shared__ __align__(16) unsigned short As[2][BM * 64];
    __shared__ __align__(16) unsigned short Bs[2][256 * 64];

    const int z = blockIdx.z;
    A  += (size_t)z * K;
    Bt += (size_t)z * K;
    C  += (size_t)z * ((size_t)M * N);

    const int tid  = threadIdx.x;
    const int w    = tid >> 6, lane = tid & 63;
    const int l15  = lane & 15, quad = lane >> 4;
    const int wm   = w >> 2, wn = w & 3;            // 2M x 4N wave grid
    const int m0   = blockIdx.y * BM, n0 = blockIdx.x * 256;
    const int NT   = K >> 6;

    const int srow = lane >> 3;
    const int schk = (lane & 7) ^ srow;
    const int rsw  = l15 & 7;                        // read-side swizzle key

    f32x4 acc[2][MI][2][2];                          // [mh][mi][nh][nj]
    #pragma unroll
    for (int mh = 0; mh < 2; ++mh)
        #pragma unroll
        for (int mi = 0; mi < MI; ++mi)
            #pragma unroll
            for (int nh = 0; nh < 2; ++nh)
                #pragma unroll
                for (int nj = 0; nj < 2; ++nj)
                    acc[mh][mi][nh][nj] = (f32x4){0.f, 0.f, 0.f, 0.f};

    bf16x8 aA[AMH][MI][2];
    bf16x8 b0[2][2], b1[2][2];

    auto stage = [&](int tile, int type) {
        if (tile >= NT) return;
        const int buf = tile & 1;
        unsigned short* dst; const unsigned short* src; int r0;
        if (BM == 256) {
            if      (type == 0) { dst = &As[buf][0];        src = A;  r0 = m0; }
            else if (type == 1) { dst = &Bs[buf][0];        src = Bt; r0 = n0; }
            else if (type == 2) { dst = &Bs[buf][128 * 64]; src = Bt; r0 = n0 + 128; }
            else                { dst = &As[buf][128 * 64]; src = A;  r0 = m0 + 128; }
        } else {
            if      (type == 0) { dst = &Bs[buf][0];        src = Bt; r0 = n0; }
            else if (type == 1) { dst = &As[buf][0];        src = A;  r0 = m0; }
            else                { dst = &Bs[buf][128 * 64]; src = Bt; r0 = n0 + 128; }
        }
        const int k0 = tile * 64;
        #pragma unroll
        for (int g = 0; g < 2; ++g) {
            const int r = w * 16 + g * 8 + srow;
            gload_lds16(src + (size_t)(r0 + r) * Kld + k0 + schk * 8,
                        dst + (w * 16 + g * 8) * 64);
        }
    };
    auto rdA = [&](int buf, int mh, int amh) {
        const unsigned short* base = &As[buf][(BM == 256 && mh) ? 128 * 64 : 0];
        #pragma unroll
        for (int mi = 0; mi < MI; ++mi) {
            const int row = (BM == 256) ? (wm * 64 + mi * 16 + l15)
                                        : (wm * 64 + mh * 32 + mi * 16 + l15);
            const unsigned short* rp = base + row * 64;
            aA[amh][mi][0] = *reinterpret_cast<const bf16x8*>(rp + ((quad    ) ^ rsw) * 8);
            aA[amh][mi][1] = *reinterpret_cast<const bf16x8*>(rp + ((quad + 4) ^ rsw) * 8);
        }
    };
    auto rdB = [&](int buf, int nh, bf16x8 (&b)[2][2]) {
        const unsigned short* base = &Bs[buf][nh ? 128 * 64 : 0];
        #pragma unroll
        for (int nj = 0; nj < 2; ++nj) {
            const int row = wn * 32 + nj * 16 + l15;
            const unsigned short* rp = base + row * 64;
            b[nj][0] = *reinterpret_cast<const bf16x8*>(rp + ((quad    ) ^ rsw) * 8);
            b[nj][1] = *reinterpret_cast<const bf16x8*>(rp + ((quad + 4) ^ rsw) * 8);
        }
    };
    auto mm = [&](int mh, int amh, int nh, bf16x8 (&b)[2][2]) {
        __builtin_amdgcn_s_setprio(1);
        #pragma unroll
        for (int mi = 0; mi < MI; ++mi)
            #pragma unroll
            for (int nj = 0; nj < 2; ++nj) {
                acc[mh][mi][nh][nj] = __builtin_amdgcn_mfma_f32_16x16x32_bf16(
                    aA[amh][mi][0], b[nj][0], acc[mh][mi][nh][nj], 0, 0, 0);
                acc[mh][mi][nh][nj] = __builtin_amdgcn_mfma_f32_16x16x32_bf16(
                    aA[amh][mi][1], b[nj][1], acc[mh][mi][nh][nj], 0, 0, 0);
            }
        __builtin_amdgcn_s_setprio(0);
    };

    // prologue: stage tile0 fully + first (BM==256 ? 3 : 2) units of tile1
    if (BM == 256) {
        stage(0, 0); stage(0, 1); stage(0, 2); stage(0, 3);
        stage(1, 0); stage(1, 1); stage(1, 2);
    } else {
        stage(0, 0); stage(0, 1); stage(0, 2);
        stage(1, 0); stage(1, 1);
    }

    for (int t = 0; t < NT; ++t) {
        const int cur = t & 1;
        if (t == NT - 1)    asm volatile("s_waitcnt vmcnt(0)" ::: "memory");
        else if (BM == 256) asm volatile("s_waitcnt vmcnt(6)" ::: "memory");
        else                asm volatile("s_waitcnt vmcnt(4)" ::: "memory");
        __builtin_amdgcn_s_barrier();

        if (BM == 256) {
            rdA(cur, 0, 0); rdB(cur, 0, b0); stage(t + 1, 3);
            __builtin_amdgcn_s_barrier();
            asm volatile("s_waitcnt lgkmcnt(0)" ::: "memory");
            mm(0, 0, 0, b0);
            __builtin_amdgcn_s_barrier();
            rdB(cur, 1, b1); stage(t + 2, 0);
            __builtin_amdgcn_s_barrier();
            asm volatile("s_waitcnt lgkmcnt(0)" ::: "memory");
            mm(0, 0, 1, b1);
            __builtin_amdgcn_s_barrier();
            rdA(cur, 1, 0); stage(t + 2, 1);
            __builtin_amdgcn_s_barrier();
            asm volatile("s_waitcnt lgkmcnt(0)" ::: "memory");
            mm(1, 0, 0, b0);
            __builtin_amdgcn_s_barrier();
            stage(t + 2, 2);
            __builtin_amdgcn_s_barrier();
            asm volatile("s_waitcnt lgkmcnt(0)" ::: "memory");
            mm(1, 0, 1, b1);
        } else {
            rdA(cur, 0, 0); rdA(cur, 1, 1); rdB(cur, 0, b0); stage(t + 1, 2);
            __builtin_amdgcn_s_barrier();
            asm volatile("s_waitcnt lgkmcnt(0)" ::: "memory");
            mm(0, 0, 0, b0); mm(1, 1, 0, b0);
            __builtin_amdgcn_s_barrier();
            rdB(cur, 1, b1); stage(t + 2, 0); stage(t + 2, 1);
            __builtin_amdgcn_s_barrier();
            asm volatile("s_waitcnt lgkmcnt(0)" ::: "memory");
            mm(0, 0, 1, b1); mm(1, 1, 1, b1);
        }
    }

    #pragma unroll
    for (int mh = 0; mh < 2; ++mh)
        #pragma unroll
        for (int mi = 0; mi < MI; ++mi) {
            const int mrow = (BM == 256) ? (mh * 128 + wm * 64 + mi * 16)
                                         : (wm * 64 + mh * 32 + mi * 16);
            #pragma unroll
            for (int r = 0; r < 4; ++r) {
                const int m = m0 + mrow + quad * 4 + r;
                #pragma unroll
                for (int nh = 0; nh < 2; ++nh)
                    #pragma unroll
                    for (int nj = 0; nj < 2; ++nj) {
                        const int n = n0 + nh * 128 + wn * 32 + nj * 16 + l15;
                        float v = acc[mh][mi][nh][nj][r];
                        if (bias) v += bias[n];
                        if (RELU) v = fmaxf(v, 0.0f);
                        size_t o;
                        if (OMODE == 2) {
                            int mat = n >> 10, nn = n & 1023;
                            int b = m >> 11, s = m & 2047;
                            int h = nn >> 6, dk = nn & 63;
                            o = (size_t)mat * QKV_STRIDE + (((size_t)b * H_ + h) * S_ + s) * DK_ + dk;
                        } else {
                            o = (size_t)m * N + n;
                        }
                        C[o] = f2bf(v);
                    }
            }
        }
}

// ---------- wave reduction ----------
__device__ __forceinline__ float wave_sum(float v) {
    #pragma unroll
    for (int off = 32; off > 0; off >>= 1) v += __shfl_down(v, off, 64);
    return v;
}

// ---------- flash attention v4 (MFMA): XOR-swizzled LDS, K via global_load_lds,
// one barrier per kv tile. One block = (bh, 128-query tile), 4 waves x 32 q.
// All LDS tiles are [row][64] bf16 (128 B rows) with 16B-chunk swizzle
// chunk' = chunk ^ (row&7) — the m201-verified conflict-free pattern for the
// frag-read (16 lanes read 16 rows at one chunk position).
// Hazard ledger (1 barrier/tile): Ps is per-wave (lgkm ordering only);
// K-DMA(t+1)/Vt-write(t+1 buf) issue AFTER sync(t) (readers of that buf
// finished before sync(t)); their readers at t+1 run after sync(t+1) whose
// implicit vmcnt(0)+lgkmcnt(0) drain retires the DMA.
constexpr int TQ_ = 128;
constexpr int TK_ = 64;
constexpr int NT_ = S_ / TK_;  // 32 kv tiles

__global__ __launch_bounds__(256)
void fattn_k(const unsigned short* __restrict__ Qm, const unsigned short* __restrict__ Km,
             const unsigned short* __restrict__ Vm, unsigned short* __restrict__ O)
{
    const int bh  = blockIdx.x >> 4;     // 16 q-tiles per (b,h)
    const int qt  = blockIdx.x & 15;
    const int tid = threadIdx.x;
    const int w = tid >> 6, lane = tid & 63;
    const int quad = lane >> 4, l15 = lane & 15;
    const int sw = l15 & 7;                          // read-side swizzle key

    __shared__ __align__(16) unsigned short Ks[2][TK_][64];   // K tile [kpos][d]
    __shared__ __align__(16) unsigned short Vt[2][80][64];    // V^T [d][col'] + ones rows 64..79
    __shared__ __align__(16) unsigned short Ps[4][32][64];    // per-wave P [q][col']

    bf16x8 qf[2][2];
    #pragma unroll
    for (int i = 0; i < 2; ++i) {
        const unsigned short* qp = Qm + ((size_t)bh * S_ + qt * TQ_ + w * 32 + i * 16 + l15) * DK_;
        qf[i][0] = *reinterpret_cast<const bf16x8*>(qp + quad * 8);
        qf[i][1] = *reinterpret_cast<const bf16x8*>(qp + 32 + quad * 8);
    }

    f32x4 o[2][4];
    f32x4 o4[2];
    #pragma unroll
    for (int i = 0; i < 2; ++i) {
        #pragma unroll
        for (int n = 0; n < 4; ++n) o[i][n] = (f32x4){0.f, 0.f, 0.f, 0.f};
        o4[i] = (f32x4){0.f, 0.f, 0.f, 0.f};
    }

    const unsigned short* kg0 = Km + (size_t)bh * S_ * DK_;
    const unsigned short* vg0 = Vm + (size_t)bh * S_ * DK_;
    const int dgrp = tid >> 4;     // 0..15 (d-group of 4 dims)
    const int vkp  = tid & 15;     // k-position low bits
    const int srow = lane >> 3;               // DMA: lane -> row within 8-row group
    const int schk = (lane & 7) ^ srow;       // pre-swizzled source chunk

    // K tile DMA: wave w stages rows [w*16, w*16+16), linear LDS dest,
    // swizzle applied on the global source address (m173 pattern).
    auto stageK = [&](int t, int buf) {
        const unsigned short* src = kg0 + (size_t)t * TK_ * DK_;
        #pragma unroll
        for (int g = 0; g < 2; ++g) {
            const int r0 = w * 16 + g * 8;
            gload_lds16(src + (size_t)(r0 + srow) * DK_ + schk * 8, &Ks[buf][r0][0]);
        }
    };
    auto loadV = [&](int t, ushort4 (&vp)[4]) {
        const unsigned short* vg = vg0 + (size_t)t * TK_ * DK_;
        #pragma unroll
        for (int p = 0; p < 4; ++p)
            vp[p] = reinterpret_cast<const ushort4*>(vg + (size_t)(vkp + p * 16) * DK_)[dgrp];
    };
    // V^T store with swizzle: row R = dgrp*4+c, logical byte 8*vkp ->
    // chunk cs = vkp>>1, half ch; swizzled byte = ((cs ^ (R&7))<<4) + ch.
    auto storeVt = [&](int buf, ushort4 (&vp)[4]) {
        char* base = reinterpret_cast<char*>(&Vt[buf][dgrp * 4][0]);
        const int cs = vkp >> 1, ch = (vkp & 1) << 3;
        ushort4 pk;
        pk.x = vp[0].x; pk.y = vp[1].x; pk.z = vp[2].x; pk.w = vp[3].x;
        *reinterpret_cast<ushort4*>(base + 0 * 128 + (((cs ^ ((dgrp * 4 + 0) & 7)) << 4) + ch)) = pk;
        pk.x = vp[0].y; pk.y = vp[1].y; pk.z = vp[2].y; pk.w = vp[3].y;
        *reinterpret_cast<ushort4*>(base + 1 * 128 + (((cs ^ ((dgrp * 4 + 1) & 7)) << 4) + ch)) = pk;
        pk.x = vp[0].z; pk.y = vp[1].z; pk.z = vp[2].z; pk.w = vp[3].z;
        *reinterpret_cast<ushort4*>(base + 2 * 128 + (((cs ^ ((dgrp * 4 + 2) & 7)) << 4) + ch)) = pk;
        pk.x = vp[0].w; pk.y = vp[1].w; pk.z = vp[2].w; pk.w = vp[3].w;
        *reinterpret_cast<ushort4*>(base + 3 * 128 + (((cs ^ ((dgrp * 4 + 3) & 7)) << 4) + ch)) = pk;
    };

    // prologue: tile 0 staged; ones rows (denominator trick) init once
    stageK(0, 0);
    {
        ushort4 vp0[4];
        loadV(0, vp0);
        storeVt(0, vp0);
        for (int idx = tid; idx < 2 * 16 * 64; idx += 256) {
            const int b  = idx >> 10;
            const int rr = (idx >> 6) & 15;
            const int cc = idx & 63;
            Vt[b][64 + rr][((cc >> 3) ^ (rr & 7)) * 8 + (cc & 7)] =
                (rr == 0) ? (unsigned short)0x3F80 : (unsigned short)0;
        }
    }

    for (int t = 0; t < NT_; ++t) {
        const int cur = t & 1, nxt = cur ^ 1;
        __syncthreads();   // drains vmcnt (K-DMA landed) + orders all LDS

        const bool hn = (t + 1 < NT_);
        ushort4 vp[4];
        if (hn) { stageK(t + 1, nxt); loadV(t + 1, vp); }

        // QK^T: rows n*16+l15 of Ks, chunks quad^sw / (quad+4)^sw
        f32x4 s[2][4];
        __builtin_amdgcn_s_setprio(1);
        #pragma unroll
        for (int n = 0; n < 4; ++n) {
            const unsigned short* kp = &Ks[cur][n * 16 + l15][0];
            bf16x8 b0 = *reinterpret_cast<const bf16x8*>(kp + ((quad ^ sw) << 3));
            bf16x8 b1 = *reinterpret_cast<const bf16x8*>(kp + (((quad + 4) ^ sw) << 3));
            #pragma unroll
            for (int i = 0; i < 2; ++i) {
                f32x4 a2 = (f32x4){0.f, 0.f, 0.f, 0.f};
                a2 = __builtin_amdgcn_mfma_f32_16x16x32_bf16(qf[i][0], b0, a2, 0, 0, 0);
                a2 = __builtin_amdgcn_mfma_f32_16x16x32_bf16(qf[i][1], b1, a2, 0, 0, 0);
                s[i][n] = a2;
            }
        }
        __builtin_amdgcn_s_setprio(0);

        // softmax exp + P write (per-wave LDS, no barrier needed)
        #pragma unroll
        for (int i = 0; i < 2; ++i)
            #pragma unroll
            for (int r = 0; r < 4; ++r) {
                ushort4 pk;
                pk.x = f2bf_rz(__expf(s[i][0][r] * 0.125f));
                pk.y = f2bf_rz(__expf(s[i][1][r] * 0.125f));
                pk.z = f2bf_rz(__expf(s[i][2][r] * 0.125f));
                pk.w = f2bf_rz(__expf(s[i][3][r] * 0.125f));
                const int R = i * 16 + quad * 4 + r;
                *reinterpret_cast<ushort4*>(
                    reinterpret_cast<char*>(&Ps[w][R][0]) +
                    ((((l15 >> 1) ^ (R & 7)) << 4) + ((l15 & 1) << 3))) = pk;
            }

        if (hn) storeVt(nxt, vp);

        // PV
        bf16x8 pa[2][2];
        #pragma unroll
        for (int i = 0; i < 2; ++i) {
            const unsigned short* pp = &Ps[w][i * 16 + l15][0];
            pa[i][0] = *reinterpret_cast<const bf16x8*>(pp + ((quad ^ sw) << 3));
            pa[i][1] = *reinterpret_cast<const bf16x8*>(pp + (((quad + 4) ^ sw) << 3));
        }
        __builtin_amdgcn_s_setprio(1);
        #pragma unroll
        for (int n = 0; n < 4; ++n) {
            const unsigned short* vb = &Vt[cur][n * 16 + l15][0];
            bf16x8 vb0 = *reinterpret_cast<const bf16x8*>(vb + ((quad ^ sw) << 3));
            bf16x8 vb1 = *reinterpret_cast<const bf16x8*>(vb + (((quad + 4) ^ sw) << 3));
            #pragma unroll
            for (int i = 0; i < 2; ++i) {
                o[i][n] = __builtin_amdgcn_mfma_f32_16x16x32_bf16(pa[i][0], vb0, o[i][n], 0, 0, 0);
                o[i][n] = __builtin_amdgcn_mfma_f32_16x16x32_bf16(pa[i][1], vb1, o[i][n], 0, 0, 0);
            }
        }
        {
            const unsigned short* vb = &Vt[cur][64 + l15][0];
            bf16x8 vb40 = *reinterpret_cast<const bf16x8*>(vb + ((quad ^ sw) << 3));
            bf16x8 vb41 = *reinterpret_cast<const bf16x8*>(vb + (((quad + 4) ^ sw) << 3));
            #pragma unroll
            for (int i = 0; i < 2; ++i) {
                o4[i] = __builtin_amdgcn_mfma_f32_16x16x32_bf16(pa[i][0], vb40, o4[i], 0, 0, 0);
                o4[i] = __builtin_amdgcn_mfma_f32_16x16x32_bf16(pa[i][1], vb41, o4[i], 0, 0, 0);
            }
        }
        __builtin_amdgcn_s_setprio(0);
    }

    const int b = bh >> 4, h = bh & 15;
    #pragma unroll
    for (int i = 0; i < 2; ++i)
        #pragma unroll
        for (int r = 0; r < 4; ++r) {
            float lrv = __shfl(o4[i][r], lane & 0x30, 64);
            float inv = 1.0f / lrv;
            int q = qt * TQ_ + w * 32 + i * 16 + quad * 4 + r;
            unsigned short* op = O + ((size_t)b * S_ + q) * D_ + h * DK_;
            #pragma unroll
            for (int n = 0; n < 4; ++n)
                op[n * 16 + l15] = f2bf(o[i][n][r] * inv);
        }
}

// ---------- reducing LayerNorm: v = P0+P1 (+bias) (+res), then LN (ddof=1) ----------
template<bool HAS_BIAS, bool RES_F32, bool OUT_F32>
__global__ __launch_bounds__(256)
void lnr_k(const unsigned short* __restrict__ P0, const unsigned short* __restrict__ P1,
           const void* __restrict__ res, const float* __restrict__ bias,
           const float* __restrict__ gp, const float* __restrict__ bp,
           void* __restrict__ Out)
{
    const int row = blockIdx.x;
    const int tid = threadIdx.x;
    const int lane = tid & 63, wave = tid >> 6;
    __shared__ float rs[4], rss[4];

    const size_t i4 = (size_t)row * 256 + tid;
    const ushort4 a = reinterpret_cast<const ushort4*>(P0)[i4];
    const ushort4 b = reinterpret_cast<const ushort4*>(P1)[i4];
    float v0 = bf2f(a.x) + bf2f(b.x);
    float v1 = bf2f(a.y) + bf2f(b.y);
    float v2 = bf2f(a.z) + bf2f(b.z);
    float v3 = bf2f(a.w) + bf2f(b.w);
    if (RES_F32) {
        float4 rv = reinterpret_cast<const float4*>(res)[i4];
        v0 += rv.x; v1 += rv.y; v2 += rv.z; v3 += rv.w;
    } else {
        ushort4 rv = reinterpret_cast<const ushort4*>(res)[i4];
        v0 += bf2f(rv.x); v1 += bf2f(rv.y); v2 += bf2f(rv.z); v3 += bf2f(rv.w);
    }
    if (HAS_BIAS) {
        float4 bv = reinterpret_cast<const float4*>(bias)[tid];
        v0 += bv.x; v1 += bv.y; v2 += bv.z; v3 += bv.w;
    }

    float s  = v0 + v1 + v2 + v3;
    float ss = v0*v0 + v1*v1 + v2*v2 + v3*v3;
    s = wave_sum(s);
    ss = wave_sum(ss);
    if (lane == 0) { rs[wave] = s; rss[wave] = ss; }
    __syncthreads();
    const float stot  = rs[0] + rs[1] + rs[2] + rs[3];
    const float sstot = rss[0] + rss[1] + rss[2] + rss[3];
    const float mean = stot / (float)D_;
    const float var  = (sstot - (float)D_ * mean * mean) / (float)(D_ - 1);
    const float scl = gp[0] * rsqrtf(var + EPS_);
    const float be = bp[0];

    float o0 = (v0 - mean) * scl + be;
    float o1 = (v1 - mean) * scl + be;
    float o2 = (v2 - mean) * scl + be;
    float o3 = (v3 - mean) * scl + be;
    if (OUT_F32) {
        reinterpret_cast<float4*>(Out)[i4] = make_float4(o0, o1, o2, o3);
    } else {
        ushort4 o;
        o.x = f2bf(o0); o.y = f2bf(o1); o.z = f2bf(o2); o.w = f2bf(o3);
        reinterpret_cast<ushort4*>(Out)[i4] = o;
    }
}

// ---------- host launch ----------
extern "C" void kernel_launch(void* const* d_in, const int* in_sizes, int n_in,
                              void* d_out, int out_size, void* d_ws, size_t ws_size,
                              hipStream_t stream)
{
    const float* x   = (const float*)d_in[0];
    const float* wq  = (const float*)d_in[2];
    const float* wk  = (const float*)d_in[3];
    const float* wv  = (const float*)d_in[4];
    const float* wo  = (const float*)d_in[5];
    const float* w1  = (const float*)d_in[6];
    const float* b1  = (const float*)d_in[7];
    const float* w2  = (const float*)d_in[8];
    const float* b2  = (const float*)d_in[9];
    const float* g1  = (const float*)d_in[10];
    const float* be1 = (const float*)d_in[11];
    const float* g2  = (const float*)d_in[12];
    const float* be2 = (const float*)d_in[13];

    unsigned short* ws = (unsigned short*)d_ws;
    const size_t need_bytes = 32 * MEGE * 2;           // 64 MB peak
    if (ws_size < need_bytes) {
        fprintf(stderr, "kernel_launch: ws too small (%zu < %zu)\n", ws_size, need_bytes);
    }
    unsigned short* wqt = ws + 0 * MEGE;
    unsigned short* wkt = ws + 1 * MEGE;
    unsigned short* wvt = ws + 2 * MEGE;
    unsigned short* wot = ws + 3 * MEGE;
    unsigned short* w1t = ws + 4 * MEGE;
    unsigned short* w2t = ws + 8 * MEGE;
    unsigned short* xb  = ws + 12 * MEGE;
    unsigned short* Q   = ws + 16 * MEGE;  // Q,K,V contiguous (QKV_STRIDE apart)
    unsigned short* K   = ws + 20 * MEGE;
    unsigned short* V   = ws + 24 * MEGE;
    unsigned short* AO  = ws + 28 * MEGE;
    unsigned short* x1  = xb;              // LN1 output (xb dead after QKV)
    unsigned short* WP  = ws + 16 * MEGE;  // Wo split-K partials [2][M,D] over dead Q,K
    unsigned short* h1  = ws + 16 * MEGE;  // full [4096,4096] (after LN1)
    unsigned short* FP  = ws + 0 * MEGE;   // FFN-down partials [2][M,D] over dead wqt..w1t

    // 0) fused preprocessing: one launch (4 DxD + w1 + w2 transposes + x convert)
    prep_k<<<dim3(16384), 256, 0, stream>>>(wq, wk, wv, wo, w1, w2, x,
                                            wqt, wkt, wvt, wot, w1t, w2t, xb);

    // 1) fused QKV projection: 256-wide phased pipeline, 192 blocks (BM=256)
    mg2_k<256, 2, false><<<dim3(3 * D_ / 256, M_ / 256), 512, 0, stream>>>(
        xb, wqt, nullptr, Q, M_, 3 * D_, D_, D_);

    // 2) flash attention: 512 blocks
    fattn_k<<<dim3(B_ * H_ * (S_ / TQ_)), 256, 0, stream>>>(Q, K, V, AO);

    // 3) Wo split-K=2 (BM=128): 256 blocks (1/CU), partials -> WP[2][M,D]
    mg2_k<128, 0, false><<<dim3(D_ / 256, M_ / 128, 2), 512, 0, stream>>>(
        AO, wot, nullptr, WP, M_, D_, D_ / 2, D_);

    // 4) LN1 = reduce(WP0+WP1) + x residual -> x1 (bf16)
    lnr_k<false, true, false><<<dim3(M_), 256, 0, stream>>>(
        WP, WP + 4 * MEGE, x, nullptr, g1, be1, x1);

    // 5) FFN-up (BM=256): 256 blocks (1/CU)
    mg2_k<256, 0, true><<<dim3(DFF_ / 256, M_ / 256), 512, 0, stream>>>(
        x1, w1t, b1, h1, M_, DFF_, D_, D_);

    // 6) FFN-down split-K=2 (BM=128): 256 blocks, partials -> FP[2][M,D]
    mg2_k<128, 0, false><<<dim3(D_ / 256, M_ / 128, 2), 512, 0, stream>>>(
        h1, w2t, nullptr, FP, M_, D_, DFF_ / 2, DFF_);

    // 7) LN2 = reduce(FP0+FP1) + b2 + x1 residual -> fp32 output
    lnr_k<true, false, true><<<dim3(M_), 256, 0, stream>>>(
        FP, FP + 4 * MEGE, x1, b2, g2, be2, d_out);
}

// Round 5
// 325.726 us; speedup vs baseline: 1.0667x; 1.0509x over previous
//
#include <hip/hip_runtime.h>
#include <cstdio>

// Problem constants
constexpr int B_   = 2;
constexpr int S_   = 2048;
constexpr int D_   = 1024;
constexpr int H_   = 16;
constexpr int DFF_ = 4096;
constexpr int DK_  = D_ / H_;   // 64
constexpr int M_   = B_ * S_;   // 4096 tokens
constexpr float EPS_ = 1e-5f;
constexpr size_t MEGE = 1u << 20;          // 1M elems
constexpr size_t QKV_STRIDE = 4 * MEGE;    // Q->K->V slot stride (elems)
constexpr float QSCALE_ = 0.18033688011112042f;  // 0.125 * log2(e): folded into Q

typedef __attribute__((ext_vector_type(8))) short bf16x8;
typedef __attribute__((ext_vector_type(4))) float f32x4;

// ---------- bf16 helpers ----------
__device__ __forceinline__ float bf2f(unsigned int u) {
    return __uint_as_float(u << 16);
}
__device__ __forceinline__ unsigned short f2bf(float f) {          // RTNE
    unsigned int u = __float_as_uint(f);
    unsigned int r = u + 0x7fffu + ((u >> 16) & 1u);
    return (unsigned short)(r >> 16);
}
__device__ __forceinline__ unsigned short f2bf_rz(float f) {       // truncate (P matrix only)
    return (unsigned short)(__float_as_uint(f) >> 16);
}
// 2^x via native v_exp_f32 (NOT __exp2f — that name collides with glibc macros
// and has no HIP device overload; v_exp_f32 IS exp2 per ISA §3).
__device__ __forceinline__ float exp2_fast(float x) {
    float r;
    asm("v_exp_f32 %0, %1" : "=v"(r) : "v"(x));
    return r;
}

// ---------- async global->LDS, 16B per lane ----------
__device__ __forceinline__ void gload_lds16(const unsigned short* g, unsigned short* l) {
    __builtin_amdgcn_global_load_lds(
        (const __attribute__((address_space(1))) unsigned int*)g,
        (__attribute__((address_space(3))) unsigned int*)l, 16, 0, 0);
}

// ---------- fused preprocessing: 6 weight transposes + x convert, ONE launch ----
__device__ __forceinline__ void tr32(const float* __restrict__ W, unsigned short* __restrict__ Wt,
                                     int K, int N, int bx, int by, float* t /*[32*33]*/)
{
    const int tx = threadIdx.x & 31, ty = threadIdx.x >> 5;   // 32 x 8
    const int n0 = bx * 32, k0 = by * 32;
    #pragma unroll
    for (int p = 0; p < 4; ++p)
        t[(ty + p * 8) * 33 + tx] = W[(size_t)(k0 + ty + p * 8) * N + n0 + tx];
    __syncthreads();
    #pragma unroll
    for (int p = 0; p < 4; ++p)
        Wt[(size_t)(n0 + ty + p * 8) * K + k0 + tx] = f2bf(t[tx * 33 + ty + p * 8]);
}

__global__ __launch_bounds__(256)
void prep_k(const float* __restrict__ wq, const float* __restrict__ wk,
            const float* __restrict__ wv, const float* __restrict__ wo,
            const float* __restrict__ w1, const float* __restrict__ w2,
            const float* __restrict__ x,
            unsigned short* __restrict__ wqt, unsigned short* __restrict__ wkt,
            unsigned short* __restrict__ wvt, unsigned short* __restrict__ wot,
            unsigned short* __restrict__ w1t, unsigned short* __restrict__ w2t,
            unsigned short* __restrict__ xb)
{
    __shared__ float t[32 * 33];
    const int bid = blockIdx.x;
    if (bid < 4096) {
        const int z = bid >> 10, rem = bid & 1023;
        const float* W = (z == 0) ? wq : (z == 1) ? wk : (z == 2) ? wv : wo;
        unsigned short* Wt = (z == 0) ? wqt : (z == 1) ? wkt : (z == 2) ? wvt : wot;
        tr32(W, Wt, D_, D_, rem & 31, rem >> 5, t);
    } else if (bid < 8192) {
        const int rem = bid - 4096;
        tr32(w1, w1t, D_, DFF_, rem & 127, rem >> 7, t);
    } else if (bid < 12288) {
        const int rem = bid - 8192;
        tr32(w2, w2t, DFF_, D_, rem & 31, rem >> 5, t);
    } else {
        const int i = (bid - 12288) * 256 + threadIdx.x;
        float4 f = reinterpret_cast<const float4*>(x)[i];
        ushort4 u;
        u.x = f2bf(f.x); u.y = f2bf(f.y); u.z = f2bf(f.z); u.w = f2bf(f.w);
        reinterpret_cast<ushort4*>(xb)[i] = u;
    }
}

// ---------- phased MFMA GEMM: C = A[M,K] @ Bt[N,K]^T, bf16 in/out, fp32 accum ----
// (verified pipeline; OMODE==2 additionally pre-scales the Q output by QSCALE_)
template<int BM, int OMODE, bool RELU>
__global__ __launch_bounds__(512, 2)
void mg2_k(const unsigned short* __restrict__ A,
           const unsigned short* __restrict__ Bt,
           const float* __restrict__ bias,
           unsigned short* __restrict__ C,
           int M, int N, int K, int Kld)
{
    constexpr int MI  = BM / 64;            // A frags per m-half (256->4, 128->2)
    constexpr int AMH = (BM == 128) ? 2 : 1;
    __shared__ __align__(16) unsigned short As[2][BM * 64];
    __shared__ __align__(16) unsigned short Bs[2][256 * 64];

    const int z = blockIdx.z;
    A  += (size_t)z * K;
    Bt += (size_t)z * K;
    C  += (size_t)z * ((size_t)M * N);

    const int tid  = threadIdx.x;
    const int w    = tid >> 6, lane = tid & 63;
    const int l15  = lane & 15, quad = lane >> 4;
    const int wm   = w >> 2, wn = w & 3;            // 2M x 4N wave grid
    const int m0   = blockIdx.y * BM, n0 = blockIdx.x * 256;
    const int NT   = K >> 6;

    const int srow = lane >> 3;
    const int schk = (lane & 7) ^ srow;
    const int rsw  = l15 & 7;                        // read-side swizzle key

    f32x4 acc[2][MI][2][2];                          // [mh][mi][nh][nj]
    #pragma unroll
    for (int mh = 0; mh < 2; ++mh)
        #pragma unroll
        for (int mi = 0; mi < MI; ++mi)
            #pragma unroll
            for (int nh = 0; nh < 2; ++nh)
                #pragma unroll
                for (int nj = 0; nj < 2; ++nj)
                    acc[mh][mi][nh][nj] = (f32x4){0.f, 0.f, 0.f, 0.f};

    bf16x8 aA[AMH][MI][2];
    bf16x8 b0[2][2], b1[2][2];

    auto stage = [&](int tile, int type) {
        if (tile >= NT) return;
        const int buf = tile & 1;
        unsigned short* dst; const unsigned short* src; int r0;
        if (BM == 256) {
            if      (type == 0) { dst = &As[buf][0];        src = A;  r0 = m0; }
            else if (type == 1) { dst = &Bs[buf][0];        src = Bt; r0 = n0; }
            else if (type == 2) { dst = &Bs[buf][128 * 64]; src = Bt; r0 = n0 + 128; }
            else                { dst = &As[buf][128 * 64]; src = A;  r0 = m0 + 128; }
        } else {
            if      (type == 0) { dst = &Bs[buf][0];        src = Bt; r0 = n0; }
            else if (type == 1) { dst = &As[buf][0];        src = A;  r0 = m0; }
            else                { dst = &Bs[buf][128 * 64]; src = Bt; r0 = n0 + 128; }
        }
        const int k0 = tile * 64;
        #pragma unroll
        for (int g = 0; g < 2; ++g) {
            const int r = w * 16 + g * 8 + srow;
            gload_lds16(src + (size_t)(r0 + r) * Kld + k0 + schk * 8,
                        dst + (w * 16 + g * 8) * 64);
        }
    };
    auto rdA = [&](int buf, int mh, int amh) {
        const unsigned short* base = &As[buf][(BM == 256 && mh) ? 128 * 64 : 0];
        #pragma unroll
        for (int mi = 0; mi < MI; ++mi) {
            const int row = (BM == 256) ? (wm * 64 + mi * 16 + l15)
                                        : (wm * 64 + mh * 32 + mi * 16 + l15);
            const unsigned short* rp = base + row * 64;
            aA[amh][mi][0] = *reinterpret_cast<const bf16x8*>(rp + ((quad    ) ^ rsw) * 8);
            aA[amh][mi][1] = *reinterpret_cast<const bf16x8*>(rp + ((quad + 4) ^ rsw) * 8);
        }
    };
    auto rdB = [&](int buf, int nh, bf16x8 (&b)[2][2]) {
        const unsigned short* base = &Bs[buf][nh ? 128 * 64 : 0];
        #pragma unroll
        for (int nj = 0; nj < 2; ++nj) {
            const int row = wn * 32 + nj * 16 + l15;
            const unsigned short* rp = base + row * 64;
            b[nj][0] = *reinterpret_cast<const bf16x8*>(rp + ((quad    ) ^ rsw) * 8);
            b[nj][1] = *reinterpret_cast<const bf16x8*>(rp + ((quad + 4) ^ rsw) * 8);
        }
    };
    auto mm = [&](int mh, int amh, int nh, bf16x8 (&b)[2][2]) {
        __builtin_amdgcn_s_setprio(1);
        #pragma unroll
        for (int mi = 0; mi < MI; ++mi)
            #pragma unroll
            for (int nj = 0; nj < 2; ++nj) {
                acc[mh][mi][nh][nj] = __builtin_amdgcn_mfma_f32_16x16x32_bf16(
                    aA[amh][mi][0], b[nj][0], acc[mh][mi][nh][nj], 0, 0, 0);
                acc[mh][mi][nh][nj] = __builtin_amdgcn_mfma_f32_16x16x32_bf16(
                    aA[amh][mi][1], b[nj][1], acc[mh][mi][nh][nj], 0, 0, 0);
            }
        __builtin_amdgcn_s_setprio(0);
    };

    // prologue: stage tile0 fully + first (BM==256 ? 3 : 2) units of tile1
    if (BM == 256) {
        stage(0, 0); stage(0, 1); stage(0, 2); stage(0, 3);
        stage(1, 0); stage(1, 1); stage(1, 2);
    } else {
        stage(0, 0); stage(0, 1); stage(0, 2);
        stage(1, 0); stage(1, 1);
    }

    for (int t = 0; t < NT; ++t) {
        const int cur = t & 1;
        if (t == NT - 1)    asm volatile("s_waitcnt vmcnt(0)" ::: "memory");
        else if (BM == 256) asm volatile("s_waitcnt vmcnt(6)" ::: "memory");
        else                asm volatile("s_waitcnt vmcnt(4)" ::: "memory");
        __builtin_amdgcn_s_barrier();

        if (BM == 256) {
            rdA(cur, 0, 0); rdB(cur, 0, b0); stage(t + 1, 3);
            __builtin_amdgcn_s_barrier();
            asm volatile("s_waitcnt lgkmcnt(0)" ::: "memory");
            mm(0, 0, 0, b0);
            __builtin_amdgcn_s_barrier();
            rdB(cur, 1, b1); stage(t + 2, 0);
            __builtin_amdgcn_s_barrier();
            asm volatile("s_waitcnt lgkmcnt(0)" ::: "memory");
            mm(0, 0, 1, b1);
            __builtin_amdgcn_s_barrier();
            rdA(cur, 1, 0); stage(t + 2, 1);
            __builtin_amdgcn_s_barrier();
            asm volatile("s_waitcnt lgkmcnt(0)" ::: "memory");
            mm(1, 0, 0, b0);
            __builtin_amdgcn_s_barrier();
            stage(t + 2, 2);
            __builtin_amdgcn_s_barrier();
            asm volatile("s_waitcnt lgkmcnt(0)" ::: "memory");
            mm(1, 0, 1, b1);
        } else {
            rdA(cur, 0, 0); rdA(cur, 1, 1); rdB(cur, 0, b0); stage(t + 1, 2);
            __builtin_amdgcn_s_barrier();
            asm volatile("s_waitcnt lgkmcnt(0)" ::: "memory");
            mm(0, 0, 0, b0); mm(1, 1, 0, b0);
            __builtin_amdgcn_s_barrier();
            rdB(cur, 1, b1); stage(t + 2, 0); stage(t + 2, 1);
            __builtin_amdgcn_s_barrier();
            asm volatile("s_waitcnt lgkmcnt(0)" ::: "memory");
            mm(0, 0, 1, b1); mm(1, 1, 1, b1);
        }
    }

    #pragma unroll
    for (int mh = 0; mh < 2; ++mh)
        #pragma unroll
        for (int mi = 0; mi < MI; ++mi) {
            const int mrow = (BM == 256) ? (mh * 128 + wm * 64 + mi * 16)
                                         : (wm * 64 + mh * 32 + mi * 16);
            #pragma unroll
            for (int r = 0; r < 4; ++r) {
                const int m = m0 + mrow + quad * 4 + r;
                #pragma unroll
                for (int nh = 0; nh < 2; ++nh)
                    #pragma unroll
                    for (int nj = 0; nj < 2; ++nj) {
                        const int n = n0 + nh * 128 + wn * 32 + nj * 16 + l15;
                        float v = acc[mh][mi][nh][nj][r];
                        if (bias) v += bias[n];
                        if (RELU) v = fmaxf(v, 0.0f);
                        size_t o;
                        if (OMODE == 2) {
                            int mat = n >> 10, nn = n & 1023;
                            int b = m >> 11, s = m & 2047;
                            int h = nn >> 6, dk = nn & 63;
                            if (mat == 0) v *= QSCALE_;   // fold softmax scale+log2e into Q
                            o = (size_t)mat * QKV_STRIDE + (((size_t)b * H_ + h) * S_ + s) * DK_ + dk;
                        } else {
                            o = (size_t)m * N + n;
                        }
                        C[o] = f2bf(v);
                    }
            }
        }
}

// ---------- wave reduction ----------
__device__ __forceinline__ float wave_sum(float v) {
    #pragma unroll
    for (int off = 32; off > 0; off >>= 1) v += __shfl_down(v, off, 64);
    return v;
}

// ---------- flash attention v5: 8 waves x 16 q-rows (512 threads) ----------
// R2 post-mortem: 4-wave version was latency-bound at 2 waves/SIMD (grid caps
// occupancy at 8 waves/CU). Same grid, 8 waves/block -> 16 waves/CU (4/SIMD).
// Staging duties split: waves 0-3 load+transpose V, waves 4-7 DMA K via
// global_load_lds (pre-swizzled source, linear LDS dest). One barrier per kv
// tile; Ps strictly per-wave; cur/nxt buffers disjoint; each wave's own
// vmcnt/lgkm drain at the barrier retires its staging ops.
// Q arrives pre-scaled by 0.125*log2(e) -> P = exp2(s) via one v_exp_f32.
constexpr int TQ_ = 128;
constexpr int TK_ = 64;
constexpr int NT_ = S_ / TK_;  // 32 kv tiles

__global__ __launch_bounds__(512)
void fattn_k(const unsigned short* __restrict__ Qm, const unsigned short* __restrict__ Km,
             const unsigned short* __restrict__ Vm, unsigned short* __restrict__ O)
{
    const int bh  = blockIdx.x >> 4;     // 16 q-tiles per (b,h)
    const int qt  = blockIdx.x & 15;
    const int tid = threadIdx.x;
    const int w = tid >> 6, lane = tid & 63;
    const int quad = lane >> 4, l15 = lane & 15;
    const int sw = l15 & 7;                          // read-side swizzle key

    __shared__ __align__(16) unsigned short Ks[2][TK_][64];   // K tile [kpos][d]
    __shared__ __align__(16) unsigned short Vt[2][80][64];    // V^T [d][col'] + ones rows 64..79
    __shared__ __align__(16) unsigned short Ps[8][16][64];    // per-wave P [q][col']

    // Q frags: wave w owns q rows qt*128 + w*16 + [0,16)
    bf16x8 qf0, qf1;
    {
        const unsigned short* qp = Qm + ((size_t)bh * S_ + qt * TQ_ + w * 16 + l15) * DK_;
        qf0 = *reinterpret_cast<const bf16x8*>(qp + quad * 8);
        qf1 = *reinterpret_cast<const bf16x8*>(qp + 32 + quad * 8);
    }

    f32x4 o[4];
    f32x4 o4;
    #pragma unroll
    for (int n = 0; n < 4; ++n) o[n] = (f32x4){0.f, 0.f, 0.f, 0.f};
    o4 = (f32x4){0.f, 0.f, 0.f, 0.f};

    const unsigned short* kg0 = Km + (size_t)bh * S_ * DK_;
    const unsigned short* vg0 = Vm + (size_t)bh * S_ * DK_;
    const int dgrp = tid >> 4;     // (waves 0-3 only) 0..15: d-group of 4 dims
    const int vkp  = tid & 15;     // k-position low bits
    const int srow = lane >> 3;               // DMA: lane -> row within 8-row group
    const int schk = (lane & 7) ^ srow;       // pre-swizzled source chunk

    // K tile DMA (waves 4-7): wave stages rows [(w-4)*16, +16), linear dest.
    auto stageK = [&](int t, int buf) {
        const unsigned short* src = kg0 + (size_t)t * TK_ * DK_;
        const int wk = w - 4;
        #pragma unroll
        for (int g = 0; g < 2; ++g) {
            const int r0 = wk * 16 + g * 8;
            gload_lds16(src + (size_t)(r0 + srow) * DK_ + schk * 8, &Ks[buf][r0][0]);
        }
    };
    auto loadV = [&](int t, ushort4 (&vp)[4]) {
        const unsigned short* vg = vg0 + (size_t)t * TK_ * DK_;
        #pragma unroll
        for (int p = 0; p < 4; ++p)
            vp[p] = reinterpret_cast<const ushort4*>(vg + (size_t)(vkp + p * 16) * DK_)[dgrp];
    };
    // V^T store with swizzle: row R = dgrp*4+c; chunk cs = vkp>>1, half ch;
    // swizzled byte = ((cs ^ (R&7))<<4) + ch. (k-order permutation matches Ps.)
    auto storeVt = [&](int buf, ushort4 (&vp)[4]) {
        char* base = reinterpret_cast<char*>(&Vt[buf][dgrp * 4][0]);
        const int cs = vkp >> 1, ch = (vkp & 1) << 3;
        ushort4 pk;
        pk.x = vp[0].x; pk.y = vp[1].x; pk.z = vp[2].x; pk.w = vp[3].x;
        *reinterpret_cast<ushort4*>(base + 0 * 128 + (((cs ^ ((dgrp * 4 + 0) & 7)) << 4) + ch)) = pk;
        pk.x = vp[0].y; pk.y = vp[1].y; pk.z = vp[2].y; pk.w = vp[3].y;
        *reinterpret_cast<ushort4*>(base + 1 * 128 + (((cs ^ ((dgrp * 4 + 1) & 7)) << 4) + ch)) = pk;
        pk.x = vp[0].z; pk.y = vp[1].z; pk.z = vp[2].z; pk.w = vp[3].z;
        *reinterpret_cast<ushort4*>(base + 2 * 128 + (((cs ^ ((dgrp * 4 + 2) & 7)) << 4) + ch)) = pk;
        pk.x = vp[0].w; pk.y = vp[1].w; pk.z = vp[2].w; pk.w = vp[3].w;
        *reinterpret_cast<ushort4*>(base + 3 * 128 + (((cs ^ ((dgrp * 4 + 3) & 7)) << 4) + ch)) = pk;
    };

    // prologue: tile 0 staged; ones rows (denominator trick) init once
    if (w >= 4) stageK(0, 0);
    else {
        ushort4 vp0[4];
        loadV(0, vp0);
        storeVt(0, vp0);
    }
    for (int idx = tid; idx < 2 * 16 * 64; idx += 512) {
        const int b  = idx >> 10;
        const int rr = (idx >> 6) & 15;
        const int cc = idx & 63;
        Vt[b][64 + rr][((cc >> 3) ^ (rr & 7)) * 8 + (cc & 7)] =
            (rr == 0) ? (unsigned short)0x3F80 : (unsigned short)0;
    }

    for (int t = 0; t < NT_; ++t) {
        const int cur = t & 1, nxt = cur ^ 1;
        __syncthreads();   // per-wave vmcnt/lgkm drain + CU-wide LDS ordering

        const bool hn = (t + 1 < NT_);
        ushort4 vp[4];
        if (hn) { if (w >= 4) stageK(t + 1, nxt); else loadV(t + 1, vp); }

        // QK^T: 8 MFMA
        f32x4 s[4];
        __builtin_amdgcn_s_setprio(1);
        #pragma unroll
        for (int n = 0; n < 4; ++n) {
            const unsigned short* kp = &Ks[cur][n * 16 + l15][0];
            bf16x8 b0 = *reinterpret_cast<const bf16x8*>(kp + ((quad ^ sw) << 3));
            bf16x8 b1 = *reinterpret_cast<const bf16x8*>(kp + (((quad + 4) ^ sw) << 3));
            f32x4 a2 = (f32x4){0.f, 0.f, 0.f, 0.f};
            a2 = __builtin_amdgcn_mfma_f32_16x16x32_bf16(qf0, b0, a2, 0, 0, 0);
            a2 = __builtin_amdgcn_mfma_f32_16x16x32_bf16(qf1, b1, a2, 0, 0, 0);
            s[n] = a2;
        }
        __builtin_amdgcn_s_setprio(0);

        // softmax: P = exp2(s) (Q pre-scaled), write per-wave P tile
        #pragma unroll
        for (int r = 0; r < 4; ++r) {
            ushort4 pk;
            pk.x = f2bf_rz(exp2_fast(s[0][r]));
            pk.y = f2bf_rz(exp2_fast(s[1][r]));
            pk.z = f2bf_rz(exp2_fast(s[2][r]));
            pk.w = f2bf_rz(exp2_fast(s[3][r]));
            const int R = quad * 4 + r;
            *reinterpret_cast<ushort4*>(
                reinterpret_cast<char*>(&Ps[w][R][0]) +
                ((((l15 >> 1) ^ (R & 7)) << 4) + ((l15 & 1) << 3))) = pk;
        }

        if (hn && w < 4) storeVt(nxt, vp);

        // PV: 10 MFMA
        bf16x8 pa0, pa1;
        {
            const unsigned short* pp = &Ps[w][l15][0];
            pa0 = *reinterpret_cast<const bf16x8*>(pp + ((quad ^ sw) << 3));
            pa1 = *reinterpret_cast<const bf16x8*>(pp + (((quad + 4) ^ sw) << 3));
        }
        __builtin_amdgcn_s_setprio(1);
        #pragma unroll
        for (int n = 0; n < 4; ++n) {
            const unsigned short* vb = &Vt[cur][n * 16 + l15][0];
            bf16x8 vb0 = *reinterpret_cast<const bf16x8*>(vb + ((quad ^ sw) << 3));
            bf16x8 vb1 = *reinterpret_cast<const bf16x8*>(vb + (((quad + 4) ^ sw) << 3));
            o[n] = __builtin_amdgcn_mfma_f32_16x16x32_bf16(pa0, vb0, o[n], 0, 0, 0);
            o[n] = __builtin_amdgcn_mfma_f32_16x16x32_bf16(pa1, vb1, o[n], 0, 0, 0);
        }
        {
            const unsigned short* vb = &Vt[cur][64 + l15][0];
            bf16x8 vb40 = *reinterpret_cast<const bf16x8*>(vb + ((quad ^ sw) << 3));
            bf16x8 vb41 = *reinterpret_cast<const bf16x8*>(vb + (((quad + 4) ^ sw) << 3));
            o4 = __builtin_amdgcn_mfma_f32_16x16x32_bf16(pa0, vb40, o4, 0, 0, 0);
            o4 = __builtin_amdgcn_mfma_f32_16x16x32_bf16(pa1, vb41, o4, 0, 0, 0);
        }
        __builtin_amdgcn_s_setprio(0);
    }

    const int b = bh >> 4, h = bh & 15;
    #pragma unroll
    for (int r = 0; r < 4; ++r) {
        float lrv = __shfl(o4[r], lane & 0x30, 64);
        float inv = 1.0f / lrv;
        int q = qt * TQ_ + w * 16 + quad * 4 + r;
        unsigned short* op = O + ((size_t)b * S_ + q) * D_ + h * DK_;
        #pragma unroll
        for (int n = 0; n < 4; ++n)
            op[n * 16 + l15] = f2bf(o[n][r] * inv);
    }
}

// ---------- reducing LayerNorm: v = P0+P1 (+bias) (+res), then LN (ddof=1) ----------
template<bool HAS_BIAS, bool RES_F32, bool OUT_F32>
__global__ __launch_bounds__(256)
void lnr_k(const unsigned short* __restrict__ P0, const unsigned short* __restrict__ P1,
           const void* __restrict__ res, const float* __restrict__ bias,
           const float* __restrict__ gp, const float* __restrict__ bp,
           void* __restrict__ Out)
{
    const int row = blockIdx.x;
    const int tid = threadIdx.x;
    const int lane = tid & 63, wave = tid >> 6;
    __shared__ float rs[4], rss[4];

    const size_t i4 = (size_t)row * 256 + tid;
    const ushort4 a = reinterpret_cast<const ushort4*>(P0)[i4];
    const ushort4 b = reinterpret_cast<const ushort4*>(P1)[i4];
    float v0 = bf2f(a.x) + bf2f(b.x);
    float v1 = bf2f(a.y) + bf2f(b.y);
    float v2 = bf2f(a.z) + bf2f(b.z);
    float v3 = bf2f(a.w) + bf2f(b.w);
    if (RES_F32) {
        float4 rv = reinterpret_cast<const float4*>(res)[i4];
        v0 += rv.x; v1 += rv.y; v2 += rv.z; v3 += rv.w;
    } else {
        ushort4 rv = reinterpret_cast<const ushort4*>(res)[i4];
        v0 += bf2f(rv.x); v1 += bf2f(rv.y); v2 += bf2f(rv.z); v3 += bf2f(rv.w);
    }
    if (HAS_BIAS) {
        float4 bv = reinterpret_cast<const float4*>(bias)[tid];
        v0 += bv.x; v1 += bv.y; v2 += bv.z; v3 += bv.w;
    }

    float s  = v0 + v1 + v2 + v3;
    float ss = v0*v0 + v1*v1 + v2*v2 + v3*v3;
    s = wave_sum(s);
    ss = wave_sum(ss);
    if (lane == 0) { rs[wave] = s; rss[wave] = ss; }
    __syncthreads();
    const float stot  = rs[0] + rs[1] + rs[2] + rs[3];
    const float sstot = rss[0] + rss[1] + rss[2] + rss[3];
    const float mean = stot / (float)D_;
    const float var  = (sstot - (float)D_ * mean * mean) / (float)(D_ - 1);
    const float scl = gp[0] * rsqrtf(var + EPS_);
    const float be = bp[0];

    float o0 = (v0 - mean) * scl + be;
    float o1 = (v1 - mean) * scl + be;
    float o2 = (v2 - mean) * scl + be;
    float o3 = (v3 - mean) * scl + be;
    if (OUT_F32) {
        reinterpret_cast<float4*>(Out)[i4] = make_float4(o0, o1, o2, o3);
    } else {
        ushort4 o;
        o.x = f2bf(o0); o.y = f2bf(o1); o.z = f2bf(o2); o.w = f2bf(o3);
        reinterpret_cast<ushort4*>(Out)[i4] = o;
    }
}

// ---------- host launch ----------
extern "C" void kernel_launch(void* const* d_in, const int* in_sizes, int n_in,
                              void* d_out, int out_size, void* d_ws, size_t ws_size,
                              hipStream_t stream)
{
    const float* x   = (const float*)d_in[0];
    const float* wq  = (const float*)d_in[2];
    const float* wk  = (const float*)d_in[3];
    const float* wv  = (const float*)d_in[4];
    const float* wo  = (const float*)d_in[5];
    const float* w1  = (const float*)d_in[6];
    const float* b1  = (const float*)d_in[7];
    const float* w2  = (const float*)d_in[8];
    const float* b2  = (const float*)d_in[9];
    const float* g1  = (const float*)d_in[10];
    const float* be1 = (const float*)d_in[11];
    const float* g2  = (const float*)d_in[12];
    const float* be2 = (const float*)d_in[13];

    unsigned short* ws = (unsigned short*)d_ws;
    const size_t need_bytes = 32 * MEGE * 2;           // 64 MB peak
    if (ws_size < need_bytes) {
        fprintf(stderr, "kernel_launch: ws too small (%zu < %zu)\n", ws_size, need_bytes);
    }
    unsigned short* wqt = ws + 0 * MEGE;
    unsigned short* wkt = ws + 1 * MEGE;
    unsigned short* wvt = ws + 2 * MEGE;
    unsigned short* wot = ws + 3 * MEGE;
    unsigned short* w1t = ws + 4 * MEGE;
    unsigned short* w2t = ws + 8 * MEGE;
    unsigned short* xb  = ws + 12 * MEGE;
    unsigned short* Q   = ws + 16 * MEGE;  // Q,K,V contiguous (QKV_STRIDE apart)
    unsigned short* K   = ws + 20 * MEGE;
    unsigned short* V   = ws + 24 * MEGE;
    unsigned short* AO  = ws + 28 * MEGE;
    unsigned short* x1  = xb;              // LN1 output (xb dead after QKV)
    unsigned short* WP  = ws + 16 * MEGE;  // Wo split-K partials [2][M,D] over dead Q,K
    unsigned short* h1  = ws + 16 * MEGE;  // full [4096,4096] (after LN1)
    unsigned short* FP  = ws + 0 * MEGE;   // FFN-down partials [2][M,D] over dead wqt..w1t

    // 0) fused preprocessing: one launch (4 DxD + w1 + w2 transposes + x convert)
    prep_k<<<dim3(16384), 256, 0, stream>>>(wq, wk, wv, wo, w1, w2, x,
                                            wqt, wkt, wvt, wot, w1t, w2t, xb);

    // 1) fused QKV projection (Q pre-scaled by QSCALE_): 192 blocks (BM=256)
    mg2_k<256, 2, false><<<dim3(3 * D_ / 256, M_ / 256), 512, 0, stream>>>(
        xb, wqt, nullptr, Q, M_, 3 * D_, D_, D_);

    // 2) flash attention: 512 blocks x 512 threads (8 waves, 16 q-rows each)
    fattn_k<<<dim3(B_ * H_ * (S_ / TQ_)), 512, 0, stream>>>(Q, K, V, AO);

    // 3) Wo split-K=2 (BM=128): 256 blocks (1/CU), partials -> WP[2][M,D]
    mg2_k<128, 0, false><<<dim3(D_ / 256, M_ / 128, 2), 512, 0, stream>>>(
        AO, wot, nullptr, WP, M_, D_, D_ / 2, D_);

    // 4) LN1 = reduce(WP0+WP1) + x residual -> x1 (bf16)
    lnr_k<false, true, false><<<dim3(M_), 256, 0, stream>>>(
        WP, WP + 4 * MEGE, x, nullptr, g1, be1, x1);

    // 5) FFN-up (BM=256): 256 blocks (1/CU)
    mg2_k<256, 0, true><<<dim3(DFF_ / 256, M_ / 256), 512, 0, stream>>>(
        x1, w1t, b1, h1, M_, DFF_, D_, D_);

    // 6) FFN-down split-K=2 (BM=128): 256 blocks, partials -> FP[2][M,D]
    mg2_k<128, 0, false><<<dim3(D_ / 256, M_ / 128, 2), 512, 0, stream>>>(
        h1, w2t, nullptr, FP, M_, D_, DFF_ / 2, DFF_);

    // 7) LN2 = reduce(FP0+FP1) + b2 + x1 residual -> fp32 output
    lnr_k<true, false, true><<<dim3(M_), 256, 0, stream>>>(
        FP, FP + 4 * MEGE, x1, b2, g2, be2, d_out);
}

// Round 8
// 324.684 us; speedup vs baseline: 1.0701x; 1.0032x over previous
//
#include <hip/hip_runtime.h>
#include <cstdio>

// Problem constants
constexpr int B_   = 2;
constexpr int S_   = 2048;
constexpr int D_   = 1024;
constexpr int H_   = 16;
constexpr int DFF_ = 4096;
constexpr int DK_  = D_ / H_;   // 64
constexpr int M_   = B_ * S_;   // 4096 tokens
constexpr float EPS_ = 1e-5f;
constexpr size_t MEGE = 1u << 20;          // 1M elems
constexpr size_t QKV_STRIDE = 4 * MEGE;    // Q->K->V slot stride (elems)
constexpr float QSCALE_ = 0.18033688011112042f;  // 0.125 * log2(e): folded into Q

typedef __attribute__((ext_vector_type(8))) short bf16x8;
typedef __attribute__((ext_vector_type(4))) float f32x4;

// ---------- bf16 helpers ----------
__device__ __forceinline__ float bf2f(unsigned int u) {
    return __uint_as_float(u << 16);
}
__device__ __forceinline__ unsigned short f2bf(float f) {          // RTNE
    unsigned int u = __float_as_uint(f);
    unsigned int r = u + 0x7fffu + ((u >> 16) & 1u);
    return (unsigned short)(r >> 16);
}
__device__ __forceinline__ unsigned short f2bf_rz(float f) {       // truncate (P matrix only)
    return (unsigned short)(__float_as_uint(f) >> 16);
}
// 2^x via native v_exp_f32 (NOT __exp2f — glibc macro collision; v_exp_f32 IS exp2).
__device__ __forceinline__ float exp2_fast(float x) {
    float r;
    asm("v_exp_f32 %0, %1" : "=v"(r) : "v"(x));
    return r;
}

// ---------- async global->LDS, 16B per lane ----------
__device__ __forceinline__ void gload_lds16(const unsigned short* g, unsigned short* l) {
    __builtin_amdgcn_global_load_lds(
        (const __attribute__((address_space(1))) unsigned int*)g,
        (__attribute__((address_space(3))) unsigned int*)l, 16, 0, 0);
}

// ---------- fused preprocessing: 6 weight transposes + x convert, ONE launch ----
__device__ __forceinline__ void tr32(const float* __restrict__ W, unsigned short* __restrict__ Wt,
                                     int K, int N, int bx, int by, float* t /*[32*33]*/)
{
    const int tx = threadIdx.x & 31, ty = threadIdx.x >> 5;   // 32 x 8
    const int n0 = bx * 32, k0 = by * 32;
    #pragma unroll
    for (int p = 0; p < 4; ++p)
        t[(ty + p * 8) * 33 + tx] = W[(size_t)(k0 + ty + p * 8) * N + n0 + tx];
    __syncthreads();
    #pragma unroll
    for (int p = 0; p < 4; ++p)
        Wt[(size_t)(n0 + ty + p * 8) * K + k0 + tx] = f2bf(t[tx * 33 + ty + p * 8]);
}

__global__ __launch_bounds__(256)
void prep_k(const float* __restrict__ wq, const float* __restrict__ wk,
            const float* __restrict__ wv, const float* __restrict__ wo,
            const float* __restrict__ w1, const float* __restrict__ w2,
            const float* __restrict__ x,
            unsigned short* __restrict__ wqt, unsigned short* __restrict__ wkt,
            unsigned short* __restrict__ wvt, unsigned short* __restrict__ wot,
            unsigned short* __restrict__ w1t, unsigned short* __restrict__ w2t,
            unsigned short* __restrict__ xb)
{
    __shared__ float t[32 * 33];
    const int bid = blockIdx.x;
    if (bid < 4096) {
        const int z = bid >> 10, rem = bid & 1023;
        const float* W = (z == 0) ? wq : (z == 1) ? wk : (z == 2) ? wv : wo;
        unsigned short* Wt = (z == 0) ? wqt : (z == 1) ? wkt : (z == 2) ? wvt : wot;
        tr32(W, Wt, D_, D_, rem & 31, rem >> 5, t);
    } else if (bid < 8192) {
        const int rem = bid - 4096;
        tr32(w1, w1t, D_, DFF_, rem & 127, rem >> 7, t);
    } else if (bid < 12288) {
        const int rem = bid - 8192;
        tr32(w2, w2t, DFF_, D_, rem & 31, rem >> 5, t);
    } else {
        const int i = (bid - 12288) * 256 + threadIdx.x;
        float4 f = reinterpret_cast<const float4*>(x)[i];
        ushort4 u;
        u.x = f2bf(f.x); u.y = f2bf(f.y); u.z = f2bf(f.z); u.w = f2bf(f.w);
        reinterpret_cast<ushort4*>(xb)[i] = u;
    }
}

// ---------- mg3: 16-wave 256x256 MFMA GEMM (latency-hiding via 4 waves/SIMD) ----
// R5 post-mortem: mg2 256-path at 2 waves/SIMD was latency/sync-bound
// (MfmaUtil 23%, VALUBusy 18%, occ 19%). Same 256² tile + 128KB LDS, but
// 1024 threads = 16 waves (4Mx4N, 64x64/wave) -> 4 waves/SIMD; 2 phases/tile
// (one per K-half), 3 barriers/tile, 64-MFMA clusters per SIMD per phase.
// Staging: 4 gloads/wave/tile, all issued in p0 into buf[nxt] (nxt's last
// reader = tile t-1, retired before this tile's loop-top barrier); loop-top
// vmcnt(0) drains tile t's loads (issued one full tile earlier, L2-hot panels).
template<int OMODE, bool RELU>
__global__ __launch_bounds__(1024, 1)
void mg3_k(const unsigned short* __restrict__ A,
           const unsigned short* __restrict__ Bt,
           const float* __restrict__ bias,
           unsigned short* __restrict__ C,
           int M, int N, int K, int Kld)
{
    __shared__ __align__(16) unsigned short As[2][256 * 64];
    __shared__ __align__(16) unsigned short Bs[2][256 * 64];

    const int tid = threadIdx.x;
    const int w = tid >> 6, lane = tid & 63;
    const int l15 = lane & 15, quad = lane >> 4;
    const int wm = w >> 2, wn = w & 3;              // 4M x 4N wave grid
    const int m0 = blockIdx.y * 256, n0 = blockIdx.x * 256;
    const int NT = K >> 6;

    const int srow = lane >> 3;                     // DMA row within 8-row group
    const int schk = (lane & 7) ^ srow;             // pre-swizzled source chunk
    const int rsw  = l15 & 7;                       // read-side swizzle key

    f32x4 acc[4][4];
    #pragma unroll
    for (int i = 0; i < 4; ++i)
        #pragma unroll
        for (int j = 0; j < 4; ++j) acc[i][j] = (f32x4){0.f, 0.f, 0.f, 0.f};

    // wave w stages A rows [w*16,+16) and B rows [w*16,+16) of the tile
    auto stageAB = [&](int tile) {
        if (tile >= NT) return;
        const int buf = tile & 1;
        const int k0 = tile * 64;
        #pragma unroll
        for (int g = 0; g < 2; ++g) {
            const int r = w * 16 + g * 8;
            gload_lds16(A + (size_t)(m0 + r + srow) * Kld + k0 + schk * 8, &As[buf][r * 64]);
        }
        #pragma unroll
        for (int g = 0; g < 2; ++g) {
            const int r = w * 16 + g * 8;
            gload_lds16(Bt + (size_t)(n0 + r + srow) * Kld + k0 + schk * 8, &Bs[buf][r * 64]);
        }
    };

    bf16x8 a[4], b[4];
    auto rd = [&](int buf, int h) {
        #pragma unroll
        for (int i = 0; i < 4; ++i) {
            const unsigned short* rp = &As[buf][(wm * 64 + i * 16 + l15) * 64];
            a[i] = *reinterpret_cast<const bf16x8*>(rp + (((quad + 4 * h) ^ rsw) << 3));
        }
        #pragma unroll
        for (int j = 0; j < 4; ++j) {
            const unsigned short* rp = &Bs[buf][(wn * 64 + j * 16 + l15) * 64];
            b[j] = *reinterpret_cast<const bf16x8*>(rp + (((quad + 4 * h) ^ rsw) << 3));
        }
    };
    auto mm16 = [&]() {
        __builtin_amdgcn_s_setprio(1);
        #pragma unroll
        for (int i = 0; i < 4; ++i)
            #pragma unroll
            for (int j = 0; j < 4; ++j)
                acc[i][j] = __builtin_amdgcn_mfma_f32_16x16x32_bf16(a[i], b[j], acc[i][j], 0, 0, 0);
        __builtin_amdgcn_s_setprio(0);
    };

    stageAB(0);

    for (int t = 0; t < NT; ++t) {
        const int cur = t & 1;
        asm volatile("s_waitcnt vmcnt(0)" ::: "memory");  // drains tile t (issued 1 tile ago)
        __builtin_amdgcn_s_barrier();
        // p0: k-half 0 | prefetch tile t+1 into buf[cur^1]
        stageAB(t + 1);
        rd(cur, 0);
        __builtin_amdgcn_s_barrier();
        asm volatile("s_waitcnt lgkmcnt(0)" ::: "memory");
        mm16();
        // p1: k-half 1 (same buffer — no inter-phase LDS hazard, no extra barrier)
        rd(cur, 1);
        __builtin_amdgcn_s_barrier();
        asm volatile("s_waitcnt lgkmcnt(0)" ::: "memory");
        mm16();
    }

    #pragma unroll
    for (int i = 0; i < 4; ++i)
        #pragma unroll
        for (int r = 0; r < 4; ++r) {
            const int m = m0 + wm * 64 + i * 16 + quad * 4 + r;
            #pragma unroll
            for (int j = 0; j < 4; ++j) {
                const int n = n0 + wn * 64 + j * 16 + l15;
                float v = acc[i][j][r];
                if (bias) v += bias[n];
                if (RELU) v = fmaxf(v, 0.0f);
                size_t o;
                if (OMODE == 2) {
                    int mat = n >> 10, nn = n & 1023;
                    int bb = m >> 11, s = m & 2047;
                    int h = nn >> 6, dk = nn & 63;
                    if (mat == 0) v *= QSCALE_;   // fold softmax scale+log2e into Q
                    o = (size_t)mat * QKV_STRIDE + (((size_t)bb * H_ + h) * S_ + s) * DK_ + dk;
                } else {
                    o = (size_t)m * N + n;
                }
                C[o] = f2bf(v);
            }
        }
}

// ---------- phased MFMA GEMM (mg2, BM=128 path): Wo / FFN-down split-K ----------
template<int BM, int OMODE, bool RELU>
__global__ __launch_bounds__(512, 2)
void mg2_k(const unsigned short* __restrict__ A,
           const unsigned short* __restrict__ Bt,
           const float* __restrict__ bias,
           unsigned short* __restrict__ C,
           int M, int N, int K, int Kld)
{
    constexpr int MI  = BM / 64;            // A frags per m-half (256->4, 128->2)
    constexpr int AMH = (BM == 128) ? 2 : 1;
    __shared__ __align__(16) unsigned short As[2][BM * 64];
    __shared__ __align__(16) unsigned short Bs[2][256 * 64];

    const int z = blockIdx.z;
    A  += (size_t)z * K;
    Bt += (size_t)z * K;
    C  += (size_t)z * ((size_t)M * N);

    const int tid  = threadIdx.x;
    const int w    = tid >> 6, lane = tid & 63;
    const int l15  = lane & 15, quad = lane >> 4;
    const int wm   = w >> 2, wn = w & 3;            // 2M x 4N wave grid
    const int m0   = blockIdx.y * BM, n0 = blockIdx.x * 256;
    const int NT   = K >> 6;

    const int srow = lane >> 3;
    const int schk = (lane & 7) ^ srow;
    const int rsw  = l15 & 7;                        // read-side swizzle key

    f32x4 acc[2][MI][2][2];                          // [mh][mi][nh][nj]
    #pragma unroll
    for (int mh = 0; mh < 2; ++mh)
        #pragma unroll
        for (int mi = 0; mi < MI; ++mi)
            #pragma unroll
            for (int nh = 0; nh < 2; ++nh)
                #pragma unroll
                for (int nj = 0; nj < 2; ++nj)
                    acc[mh][mi][nh][nj] = (f32x4){0.f, 0.f, 0.f, 0.f};

    bf16x8 aA[AMH][MI][2];
    bf16x8 b0[2][2], b1[2][2];

    auto stage = [&](int tile, int type) {
        if (tile >= NT) return;
        const int buf = tile & 1;
        unsigned short* dst; const unsigned short* src; int r0;
        if (BM == 256) {
            if      (type == 0) { dst = &As[buf][0];        src = A;  r0 = m0; }
            else if (type == 1) { dst = &Bs[buf][0];        src = Bt; r0 = n0; }
            else if (type == 2) { dst = &Bs[buf][128 * 64]; src = Bt; r0 = n0 + 128; }
            else                { dst = &As[buf][128 * 64]; src = A;  r0 = m0 + 128; }
        } else {
            if      (type == 0) { dst = &Bs[buf][0];        src = Bt; r0 = n0; }
            else if (type == 1) { dst = &As[buf][0];        src = A;  r0 = m0; }
            else                { dst = &Bs[buf][128 * 64]; src = Bt; r0 = n0 + 128; }
        }
        const int k0 = tile * 64;
        #pragma unroll
        for (int g = 0; g < 2; ++g) {
            const int r = w * 16 + g * 8 + srow;
            gload_lds16(src + (size_t)(r0 + r) * Kld + k0 + schk * 8,
                        dst + (w * 16 + g * 8) * 64);
        }
    };
    auto rdA = [&](int buf, int mh, int amh) {
        const unsigned short* base = &As[buf][(BM == 256 && mh) ? 128 * 64 : 0];
        #pragma unroll
        for (int mi = 0; mi < MI; ++mi) {
            const int row = (BM == 256) ? (wm * 64 + mi * 16 + l15)
                                        : (wm * 64 + mh * 32 + mi * 16 + l15);
            const unsigned short* rp = base + row * 64;
            aA[amh][mi][0] = *reinterpret_cast<const bf16x8*>(rp + ((quad    ) ^ rsw) * 8);
            aA[amh][mi][1] = *reinterpret_cast<const bf16x8*>(rp + ((quad + 4) ^ rsw) * 8);
        }
    };
    auto rdB = [&](int buf, int nh, bf16x8 (&b)[2][2]) {
        const unsigned short* base = &Bs[buf][nh ? 128 * 64 : 0];
        #pragma unroll
        for (int nj = 0; nj < 2; ++nj) {
            const int row = wn * 32 + nj * 16 + l15;
            const unsigned short* rp = base + row * 64;
            b[nj][0] = *reinterpret_cast<const bf16x8*>(rp + ((quad    ) ^ rsw) * 8);
            b[nj][1] = *reinterpret_cast<const bf16x8*>(rp + ((quad + 4) ^ rsw) * 8);
        }
    };
    auto mm = [&](int mh, int amh, int nh, bf16x8 (&b)[2][2]) {
        __builtin_amdgcn_s_setprio(1);
        #pragma unroll
        for (int mi = 0; mi < MI; ++mi)
            #pragma unroll
            for (int nj = 0; nj < 2; ++nj) {
                acc[mh][mi][nh][nj] = __builtin_amdgcn_mfma_f32_16x16x32_bf16(
                    aA[amh][mi][0], b[nj][0], acc[mh][mi][nh][nj], 0, 0, 0);
                acc[mh][mi][nh][nj] = __builtin_amdgcn_mfma_f32_16x16x32_bf16(
                    aA[amh][mi][1], b[nj][1], acc[mh][mi][nh][nj], 0, 0, 0);
            }
        __builtin_amdgcn_s_setprio(0);
    };

    // prologue: stage tile0 fully + first (BM==256 ? 3 : 2) units of tile1
    if (BM == 256) {
        stage(0, 0); stage(0, 1); stage(0, 2); stage(0, 3);
        stage(1, 0); stage(1, 1); stage(1, 2);
    } else {
        stage(0, 0); stage(0, 1); stage(0, 2);
        stage(1, 0); stage(1, 1);
    }

    for (int t = 0; t < NT; ++t) {
        const int cur = t & 1;
        if (t == NT - 1)    asm volatile("s_waitcnt vmcnt(0)" ::: "memory");
        else if (BM == 256) asm volatile("s_waitcnt vmcnt(6)" ::: "memory");
        else                asm volatile("s_waitcnt vmcnt(4)" ::: "memory");
        __builtin_amdgcn_s_barrier();

        if (BM == 256) {
            rdA(cur, 0, 0); rdB(cur, 0, b0); stage(t + 1, 3);
            __builtin_amdgcn_s_barrier();
            asm volatile("s_waitcnt lgkmcnt(0)" ::: "memory");
            mm(0, 0, 0, b0);
            __builtin_amdgcn_s_barrier();
            rdB(cur, 1, b1); stage(t + 2, 0);
            __builtin_amdgcn_s_barrier();
            asm volatile("s_waitcnt lgkmcnt(0)" ::: "memory");
            mm(0, 0, 1, b1);
            __builtin_amdgcn_s_barrier();
            rdA(cur, 1, 0); stage(t + 2, 1);
            __builtin_amdgcn_s_barrier();
            asm volatile("s_waitcnt lgkmcnt(0)" ::: "memory");
            mm(1, 0, 0, b0);
            __builtin_amdgcn_s_barrier();
            stage(t + 2, 2);
            __builtin_amdgcn_s_barrier();
            asm volatile("s_waitcnt lgkmcnt(0)" ::: "memory");
            mm(1, 0, 1, b1);
        } else {
            rdA(cur, 0, 0); rdA(cur, 1, 1); rdB(cur, 0, b0); stage(t + 1, 2);
            __builtin_amdgcn_s_barrier();
            asm volatile("s_waitcnt lgkmcnt(0)" ::: "memory");
            mm(0, 0, 0, b0); mm(1, 1, 0, b0);
            __builtin_amdgcn_s_barrier();
            rdB(cur, 1, b1); stage(t + 2, 0); stage(t + 2, 1);
            __builtin_amdgcn_s_barrier();
            asm volatile("s_waitcnt lgkmcnt(0)" ::: "memory");
            mm(0, 0, 1, b1); mm(1, 1, 1, b1);
        }
    }

    #pragma unroll
    for (int mh = 0; mh < 2; ++mh)
        #pragma unroll
        for (int mi = 0; mi < MI; ++mi) {
            const int mrow = (BM == 256) ? (mh * 128 + wm * 64 + mi * 16)
                                         : (wm * 64 + mh * 32 + mi * 16);
            #pragma unroll
            for (int r = 0; r < 4; ++r) {
                const int m = m0 + mrow + quad * 4 + r;
                #pragma unroll
                for (int nh = 0; nh < 2; ++nh)
                    #pragma unroll
                    for (int nj = 0; nj < 2; ++nj) {
                        const int n = n0 + nh * 128 + wn * 32 + nj * 16 + l15;
                        float v = acc[mh][mi][nh][nj][r];
                        if (bias) v += bias[n];
                        if (RELU) v = fmaxf(v, 0.0f);
                        size_t o;
                        if (OMODE == 2) {
                            int mat = n >> 10, nn = n & 1023;
                            int b = m >> 11, s = m & 2047;
                            int h = nn >> 6, dk = nn & 63;
                            if (mat == 0) v *= QSCALE_;
                            o = (size_t)mat * QKV_STRIDE + (((size_t)b * H_ + h) * S_ + s) * DK_ + dk;
                        } else {
                            o = (size_t)m * N + n;
                        }
                        C[o] = f2bf(v);
                    }
            }
        }
}

// ---------- wave reduction ----------
__device__ __forceinline__ float wave_sum(float v) {
    #pragma unroll
    for (int off = 32; off > 0; off >>= 1) v += __shfl_down(v, off, 64);
    return v;
}

// ---------- flash attention v5: 8 waves x 16 q-rows (512 threads) ----------
constexpr int TQ_ = 128;
constexpr int TK_ = 64;
constexpr int NT_ = S_ / TK_;  // 32 kv tiles

__global__ __launch_bounds__(512)
void fattn_k(const unsigned short* __restrict__ Qm, const unsigned short* __restrict__ Km,
             const unsigned short* __restrict__ Vm, unsigned short* __restrict__ O)
{
    const int bh  = blockIdx.x >> 4;     // 16 q-tiles per (b,h)
    const int qt  = blockIdx.x & 15;
    const int tid = threadIdx.x;
    const int w = tid >> 6, lane = tid & 63;
    const int quad = lane >> 4, l15 = lane & 15;
    const int sw = l15 & 7;                          // read-side swizzle key

    __shared__ __align__(16) unsigned short Ks[2][TK_][64];   // K tile [kpos][d]
    __shared__ __align__(16) unsigned short Vt[2][80][64];    // V^T [d][col'] + ones rows 64..79
    __shared__ __align__(16) unsigned short Ps[8][16][64];    // per-wave P [q][col']

    // Q frags: wave w owns q rows qt*128 + w*16 + [0,16)
    bf16x8 qf0, qf1;
    {
        const unsigned short* qp = Qm + ((size_t)bh * S_ + qt * TQ_ + w * 16 + l15) * DK_;
        qf0 = *reinterpret_cast<const bf16x8*>(qp + quad * 8);
        qf1 = *reinterpret_cast<const bf16x8*>(qp + 32 + quad * 8);
    }

    f32x4 o[4];
    f32x4 o4;
    #pragma unroll
    for (int n = 0; n < 4; ++n) o[n] = (f32x4){0.f, 0.f, 0.f, 0.f};
    o4 = (f32x4){0.f, 0.f, 0.f, 0.f};

    const unsigned short* kg0 = Km + (size_t)bh * S_ * DK_;
    const unsigned short* vg0 = Vm + (size_t)bh * S_ * DK_;
    const int dgrp = tid >> 4;     // (waves 0-3 only) 0..15: d-group of 4 dims
    const int vkp  = tid & 15;     // k-position low bits
    const int srow = lane >> 3;               // DMA: lane -> row within 8-row group
    const int schk = (lane & 7) ^ srow;       // pre-swizzled source chunk

    auto stageK = [&](int t, int buf) {
        const unsigned short* src = kg0 + (size_t)t * TK_ * DK_;
        const int wk = w - 4;
        #pragma unroll
        for (int g = 0; g < 2; ++g) {
            const int r0 = wk * 16 + g * 8;
            gload_lds16(src + (size_t)(r0 + srow) * DK_ + schk * 8, &Ks[buf][r0][0]);
        }
    };
    auto loadV = [&](int t, ushort4 (&vp)[4]) {
        const unsigned short* vg = vg0 + (size_t)t * TK_ * DK_;
        #pragma unroll
        for (int p = 0; p < 4; ++p)
            vp[p] = reinterpret_cast<const ushort4*>(vg + (size_t)(vkp + p * 16) * DK_)[dgrp];
    };
    auto storeVt = [&](int buf, ushort4 (&vp)[4]) {
        char* base = reinterpret_cast<char*>(&Vt[buf][dgrp * 4][0]);
        const int cs = vkp >> 1, ch = (vkp & 1) << 3;
        ushort4 pk;
        pk.x = vp[0].x; pk.y = vp[1].x; pk.z = vp[2].x; pk.w = vp[3].x;
        *reinterpret_cast<ushort4*>(base + 0 * 128 + (((cs ^ ((dgrp * 4 + 0) & 7)) << 4) + ch)) = pk;
        pk.x = vp[0].y; pk.y = vp[1].y; pk.z = vp[2].y; pk.w = vp[3].y;
        *reinterpret_cast<ushort4*>(base + 1 * 128 + (((cs ^ ((dgrp * 4 + 1) & 7)) << 4) + ch)) = pk;
        pk.x = vp[0].z; pk.y = vp[1].z; pk.z = vp[2].z; pk.w = vp[3].z;
        *reinterpret_cast<ushort4*>(base + 2 * 128 + (((cs ^ ((dgrp * 4 + 2) & 7)) << 4) + ch)) = pk;
        pk.x = vp[0].w; pk.y = vp[1].w; pk.z = vp[2].w; pk.w = vp[3].w;
        *reinterpret_cast<ushort4*>(base + 3 * 128 + (((cs ^ ((dgrp * 4 + 3) & 7)) << 4) + ch)) = pk;
    };

    // prologue: tile 0 staged; ones rows (denominator trick) init once
    if (w >= 4) stageK(0, 0);
    else {
        ushort4 vp0[4];
        loadV(0, vp0);
        storeVt(0, vp0);
    }
    for (int idx = tid; idx < 2 * 16 * 64; idx += 512) {
        const int b  = idx >> 10;
        const int rr = (idx >> 6) & 15;
        const int cc = idx & 63;
        Vt[b][64 + rr][((cc >> 3) ^ (rr & 7)) * 8 + (cc & 7)] =
            (rr == 0) ? (unsigned short)0x3F80 : (unsigned short)0;
    }

    for (int t = 0; t < NT_; ++t) {
        const int cur = t & 1, nxt = cur ^ 1;
        __syncthreads();   // per-wave vmcnt/lgkm drain + CU-wide LDS ordering

        const bool hn = (t + 1 < NT_);
        ushort4 vp[4];
        if (hn) { if (w >= 4) stageK(t + 1, nxt); else loadV(t + 1, vp); }

        // QK^T: 8 MFMA
        f32x4 s[4];
        __builtin_amdgcn_s_setprio(1);
        #pragma unroll
        for (int n = 0; n < 4; ++n) {
            const unsigned short* kp = &Ks[cur][n * 16 + l15][0];
            bf16x8 b0 = *reinterpret_cast<const bf16x8*>(kp + ((quad ^ sw) << 3));
            bf16x8 b1 = *reinterpret_cast<const bf16x8*>(kp + (((quad + 4) ^ sw) << 3));
            f32x4 a2 = (f32x4){0.f, 0.f, 0.f, 0.f};
            a2 = __builtin_amdgcn_mfma_f32_16x16x32_bf16(qf0, b0, a2, 0, 0, 0);
            a2 = __builtin_amdgcn_mfma_f32_16x16x32_bf16(qf1, b1, a2, 0, 0, 0);
            s[n] = a2;
        }
        __builtin_amdgcn_s_setprio(0);

        // softmax: P = exp2(s) (Q pre-scaled), write per-wave P tile
        #pragma unroll
        for (int r = 0; r < 4; ++r) {
            ushort4 pk;
            pk.x = f2bf_rz(exp2_fast(s[0][r]));
            pk.y = f2bf_rz(exp2_fast(s[1][r]));
            pk.z = f2bf_rz(exp2_fast(s[2][r]));
            pk.w = f2bf_rz(exp2_fast(s[3][r]));
            const int R = quad * 4 + r;
            *reinterpret_cast<ushort4*>(
                reinterpret_cast<char*>(&Ps[w][R][0]) +
                ((((l15 >> 1) ^ (R & 7)) << 4) + ((l15 & 1) << 3))) = pk;
        }

        if (hn && w < 4) storeVt(nxt, vp);

        // PV: 10 MFMA
        bf16x8 pa0, pa1;
        {
            const unsigned short* pp = &Ps[w][l15][0];
            pa0 = *reinterpret_cast<const bf16x8*>(pp + ((quad ^ sw) << 3));
            pa1 = *reinterpret_cast<const bf16x8*>(pp + (((quad + 4) ^ sw) << 3));
        }
        __builtin_amdgcn_s_setprio(1);
        #pragma unroll
        for (int n = 0; n < 4; ++n) {
            const unsigned short* vb = &Vt[cur][n * 16 + l15][0];
            bf16x8 vb0 = *reinterpret_cast<const bf16x8*>(vb + ((quad ^ sw) << 3));
            bf16x8 vb1 = *reinterpret_cast<const bf16x8*>(vb + (((quad + 4) ^ sw) << 3));
            o[n] = __builtin_amdgcn_mfma_f32_16x16x32_bf16(pa0, vb0, o[n], 0, 0, 0);
            o[n] = __builtin_amdgcn_mfma_f32_16x16x32_bf16(pa1, vb1, o[n], 0, 0, 0);
        }
        {
            const unsigned short* vb = &Vt[cur][64 + l15][0];
            bf16x8 vb40 = *reinterpret_cast<const bf16x8*>(vb + ((quad ^ sw) << 3));
            bf16x8 vb41 = *reinterpret_cast<const bf16x8*>(vb + (((quad + 4) ^ sw) << 3));
            o4 = __builtin_amdgcn_mfma_f32_16x16x32_bf16(pa0, vb40, o4, 0, 0, 0);
            o4 = __builtin_amdgcn_mfma_f32_16x16x32_bf16(pa1, vb41, o4, 0, 0, 0);
        }
        __builtin_amdgcn_s_setprio(0);
    }

    const int b = bh >> 4, h = bh & 15;
    #pragma unroll
    for (int r = 0; r < 4; ++r) {
        float lrv = __shfl(o4[r], lane & 0x30, 64);
        float inv = 1.0f / lrv;
        int q = qt * TQ_ + w * 16 + quad * 4 + r;
        unsigned short* op = O + ((size_t)b * S_ + q) * D_ + h * DK_;
        #pragma unroll
        for (int n = 0; n < 4; ++n)
            op[n * 16 + l15] = f2bf(o[n][r] * inv);
    }
}

// ---------- reducing LayerNorm: v = P0+P1 (+bias) (+res), then LN (ddof=1) ----------
template<bool HAS_BIAS, bool RES_F32, bool OUT_F32>
__global__ __launch_bounds__(256)
void lnr_k(const unsigned short* __restrict__ P0, const unsigned short* __restrict__ P1,
           const void* __restrict__ res, const float* __restrict__ bias,
           const float* __restrict__ gp, const float* __restrict__ bp,
           void* __restrict__ Out)
{
    const int row = blockIdx.x;
    const int tid = threadIdx.x;
    const int lane = tid & 63, wave = tid >> 6;
    __shared__ float rs[4], rss[4];

    const size_t i4 = (size_t)row * 256 + tid;
    const ushort4 a = reinterpret_cast<const ushort4*>(P0)[i4];
    const ushort4 b = reinterpret_cast<const ushort4*>(P1)[i4];
    float v0 = bf2f(a.x) + bf2f(b.x);
    float v1 = bf2f(a.y) + bf2f(b.y);
    float v2 = bf2f(a.z) + bf2f(b.z);
    float v3 = bf2f(a.w) + bf2f(b.w);
    if (RES_F32) {
        float4 rv = reinterpret_cast<const float4*>(res)[i4];
        v0 += rv.x; v1 += rv.y; v2 += rv.z; v3 += rv.w;
    } else {
        ushort4 rv = reinterpret_cast<const ushort4*>(res)[i4];
        v0 += bf2f(rv.x); v1 += bf2f(rv.y); v2 += bf2f(rv.z); v3 += bf2f(rv.w);
    }
    if (HAS_BIAS) {
        float4 bv = reinterpret_cast<const float4*>(bias)[tid];
        v0 += bv.x; v1 += bv.y; v2 += bv.z; v3 += bv.w;
    }

    float s  = v0 + v1 + v2 + v3;
    float ss = v0*v0 + v1*v1 + v2*v2 + v3*v3;
    s = wave_sum(s);
    ss = wave_sum(ss);
    if (lane == 0) { rs[wave] = s; rss[wave] = ss; }
    __syncthreads();
    const float stot  = rs[0] + rs[1] + rs[2] + rs[3];
    const float sstot = rss[0] + rss[1] + rss[2] + rss[3];
    const float mean = stot / (float)D_;
    const float var  = (sstot - (float)D_ * mean * mean) / (float)(D_ - 1);
    const float scl = gp[0] * rsqrtf(var + EPS_);
    const float be = bp[0];

    float o0 = (v0 - mean) * scl + be;
    float o1 = (v1 - mean) * scl + be;
    float o2 = (v2 - mean) * scl + be;
    float o3 = (v3 - mean) * scl + be;
    if (OUT_F32) {
        reinterpret_cast<float4*>(Out)[i4] = make_float4(o0, o1, o2, o3);
    } else {
        ushort4 o;
        o.x = f2bf(o0); o.y = f2bf(o1); o.z = f2bf(o2); o.w = f2bf(o3);
        reinterpret_cast<ushort4*>(Out)[i4] = o;
    }
}

// ---------- host launch ----------
extern "C" void kernel_launch(void* const* d_in, const int* in_sizes, int n_in,
                              void* d_out, int out_size, void* d_ws, size_t ws_size,
                              hipStream_t stream)
{
    const float* x   = (const float*)d_in[0];
    const float* wq  = (const float*)d_in[2];
    const float* wk  = (const float*)d_in[3];
    const float* wv  = (const float*)d_in[4];
    const float* wo  = (const float*)d_in[5];
    const float* w1  = (const float*)d_in[6];
    const float* b1  = (const float*)d_in[7];
    const float* w2  = (const float*)d_in[8];
    const float* b2  = (const float*)d_in[9];
    const float* g1  = (const float*)d_in[10];
    const float* be1 = (const float*)d_in[11];
    const float* g2  = (const float*)d_in[12];
    const float* be2 = (const float*)d_in[13];

    unsigned short* ws = (unsigned short*)d_ws;
    const size_t need_bytes = 32 * MEGE * 2;           // 64 MB peak
    if (ws_size < need_bytes) {
        fprintf(stderr, "kernel_launch: ws too small (%zu < %zu)\n", ws_size, need_bytes);
    }
    unsigned short* wqt = ws + 0 * MEGE;
    unsigned short* wkt = ws + 1 * MEGE;
    unsigned short* wvt = ws + 2 * MEGE;
    unsigned short* wot = ws + 3 * MEGE;
    unsigned short* w1t = ws + 4 * MEGE;
    unsigned short* w2t = ws + 8 * MEGE;
    unsigned short* xb  = ws + 12 * MEGE;
    unsigned short* Q   = ws + 16 * MEGE;  // Q,K,V contiguous (QKV_STRIDE apart)
    unsigned short* K   = ws + 20 * MEGE;
    unsigned short* V   = ws + 24 * MEGE;
    unsigned short* AO  = ws + 28 * MEGE;
    unsigned short* x1  = xb;              // LN1 output (xb dead after QKV)
    unsigned short* WP  = ws + 16 * MEGE;  // Wo split-K partials [2][M,D] over dead Q,K
    unsigned short* h1  = ws + 16 * MEGE;  // full [4096,4096] (after LN1)
    unsigned short* FP  = ws + 0 * MEGE;   // FFN-down partials [2][M,D] over dead wqt..w1t

    // 0) fused preprocessing: one launch (4 DxD + w1 + w2 transposes + x convert)
    prep_k<<<dim3(16384), 256, 0, stream>>>(wq, wk, wv, wo, w1, w2, x,
                                            wqt, wkt, wvt, wot, w1t, w2t, xb);

    // 1) fused QKV projection (Q pre-scaled): mg3 16-wave, 192 blocks x 1024 thr
    mg3_k<2, false><<<dim3(3 * D_ / 256, M_ / 256), 1024, 0, stream>>>(
        xb, wqt, nullptr, Q, M_, 3 * D_, D_, D_);

    // 2) flash attention: 512 blocks x 512 threads (8 waves, 16 q-rows each)
    fattn_k<<<dim3(B_ * H_ * (S_ / TQ_)), 512, 0, stream>>>(Q, K, V, AO);

    // 3) Wo split-K=2 (mg2 BM=128): 256 blocks, partials -> WP[2][M,D]
    mg2_k<128, 0, false><<<dim3(D_ / 256, M_ / 128, 2), 512, 0, stream>>>(
        AO, wot, nullptr, WP, M_, D_, D_ / 2, D_);

    // 4) LN1 = reduce(WP0+WP1) + x residual -> x1 (bf16)
    lnr_k<false, true, false><<<dim3(M_), 256, 0, stream>>>(
        WP, WP + 4 * MEGE, x, nullptr, g1, be1, x1);

    // 5) FFN-up: mg3 16-wave, 256 blocks x 1024 thr
    mg3_k<0, true><<<dim3(DFF_ / 256, M_ / 256), 1024, 0, stream>>>(
        x1, w1t, b1, h1, M_, DFF_, D_, D_);

    // 6) FFN-down split-K=2 (mg2 BM=128): 256 blocks, partials -> FP[2][M,D]
    mg2_k<128, 0, false><<<dim3(D_ / 256, M_ / 128, 2), 512, 0, stream>>>(
        h1, w2t, nullptr, FP, M_, D_, DFF_ / 2, DFF_);

    // 7) LN2 = reduce(FP0+FP1) + b2 + x1 residual -> fp32 output
    lnr_k<true, false, true><<<dim3(M_), 256, 0, stream>>>(
        FP, FP + 4 * MEGE, x1, b2, g2, be2, d_out);
}